// Round 1
// baseline (961.034 us; speedup 1.0000x reference)
//
#include <hip/hip_runtime.h>
#include <hip/hip_bf16.h>
#include <math.h>

#define BATCH 16384
#define NTAB 26
#define DIM 128
#define NROWS 100000

// ---------------- bottom layer 0: 13 -> 512, relu ----------------
__global__ __launch_bounds__(256) void bot0_kernel(const float* __restrict__ x,
    const float* __restrict__ W, const float* __restrict__ bias, float* __restrict__ y) {
  int b = blockIdx.x >> 1;
  int m = ((blockIdx.x & 1) << 8) | threadIdx.x;
  const float* xr = x + (size_t)b * 13;
  const float* wr = W + (size_t)m * 13;
  float acc = bias[m];
#pragma unroll
  for (int k = 0; k < 13; k++) acc = fmaf(xr[k], wr[k], acc);
  y[(size_t)b * 512 + m] = fmaxf(acc, 0.f);
}

// ---------------- embedding gather + pool (P=2) into T[:,1+t,:] ----------------
__global__ __launch_bounds__(256) void emb_pool_kernel(const float* __restrict__ tables,
    const int* __restrict__ lS_i, float* __restrict__ T) {
  int q = blockIdx.x * 8 + (threadIdx.x >> 5);   // pair id: t*B + b
  int d4 = threadIdx.x & 31;                     // float4 index within 128-dim row
  int t = q >> 14;                               // B = 16384 = 2^14
  int b = q & 16383;
  const int* idx = lS_i + ((size_t)t << 15) + (b << 1);
  int i0 = idx[0], i1 = idx[1];
  const float4* r0 = (const float4*)(tables + ((size_t)t * NROWS + (size_t)i0) * DIM);
  const float4* r1 = (const float4*)(tables + ((size_t)t * NROWS + (size_t)i1) * DIM);
  float4 v0 = r0[d4], v1 = r1[d4];
  float4 s = make_float4(v0.x + v1.x, v0.y + v1.y, v0.z + v1.z, v0.w + v1.w);
  float4* dst = (float4*)(T + ((size_t)b * 27 + 1 + t) * DIM);
  dst[d4] = s;
}

// ---------------- interaction: R[b] = [x(128), tril(T T^T, k=-1)(351)] ----------------
__global__ __launch_bounds__(256) void interact_kernel(const float* __restrict__ T,
    float* __restrict__ R) {
  int b = blockIdx.x;
  __shared__ float Ts[27 * 133];   // pad stride 133 (gcd(133%32=5,32)=1 spreads banks)
  const float* Tb = T + (size_t)b * (27 * DIM);
  for (int e = threadIdx.x; e < 27 * DIM; e += 256) {
    int r = e >> 7, d = e & 127;
    Ts[r * 133 + d] = Tb[e];
  }
  __syncthreads();
  float* Rb = R + (size_t)b * 479;
  if (threadIdx.x < DIM) Rb[threadIdx.x] = Ts[threadIdx.x];   // x = T row 0
  for (int p = threadIdx.x; p < 351; p += 256) {
    // p -> (i,j), i in 1..26, j<i, row-major tril order
    int i = (int)((sqrtf(8.f * (float)p + 1.f) + 1.f) * 0.5f);
    while (i * (i - 1) / 2 > p) --i;
    while ((i + 1) * i / 2 <= p) ++i;
    int j = p - i * (i - 1) / 2;
    const float* ti = &Ts[i * 133];
    const float* tj = &Ts[j * 133];
    float acc = 0.f;
#pragma unroll 8
    for (int d = 0; d < DIM; d++) acc = fmaf(ti[d], tj[d], acc);
    Rb[DIM + p] = acc;
  }
}

// ---------------- generic tiled fp32 GEMM: C = act(A @ W^T + bias) ----------------
// A: M x K (row-major, lda=K), W: N x K (row-major), C: M x ldc
// 64x64 tile, BK=16, 256 threads, 4x4 per thread
template <int ACT>   // 0 = none, 1 = relu
__global__ __launch_bounds__(256) void gemm_wt_kernel(const float* __restrict__ A,
    const float* __restrict__ W, const float* __restrict__ bias, float* __restrict__ C,
    int M, int N, int K, int ldc) {
  __shared__ float As[16][68];
  __shared__ float Ws[16][68];
  const int tid = threadIdx.x;
  const int tx = tid & 15, ty = tid >> 4;
  const int m0 = blockIdx.y * 64, n0 = blockIdx.x * 64;
  float acc[4][4] = {};
  for (int k0 = 0; k0 < K; k0 += 16) {
#pragma unroll
    for (int i = 0; i < 4; i++) {
      int e = tid + i * 256;
      int row = e >> 4, kk = e & 15;
      int k = k0 + kk;
      As[kk][row] = (k < K) ? A[(size_t)(m0 + row) * K + k] : 0.f;
      Ws[kk][row] = (k < K) ? W[(size_t)(n0 + row) * K + k] : 0.f;
    }
    __syncthreads();
#pragma unroll
    for (int kk = 0; kk < 16; kk++) {
      float4 a = *(const float4*)&As[kk][ty * 4];
      float4 w = *(const float4*)&Ws[kk][tx * 4];
      acc[0][0] = fmaf(a.x, w.x, acc[0][0]);
      acc[0][1] = fmaf(a.x, w.y, acc[0][1]);
      acc[0][2] = fmaf(a.x, w.z, acc[0][2]);
      acc[0][3] = fmaf(a.x, w.w, acc[0][3]);
      acc[1][0] = fmaf(a.y, w.x, acc[1][0]);
      acc[1][1] = fmaf(a.y, w.y, acc[1][1]);
      acc[1][2] = fmaf(a.y, w.z, acc[1][2]);
      acc[1][3] = fmaf(a.y, w.w, acc[1][3]);
      acc[2][0] = fmaf(a.z, w.x, acc[2][0]);
      acc[2][1] = fmaf(a.z, w.y, acc[2][1]);
      acc[2][2] = fmaf(a.z, w.z, acc[2][2]);
      acc[2][3] = fmaf(a.z, w.w, acc[2][3]);
      acc[3][0] = fmaf(a.w, w.x, acc[3][0]);
      acc[3][1] = fmaf(a.w, w.y, acc[3][1]);
      acc[3][2] = fmaf(a.w, w.z, acc[3][2]);
      acc[3][3] = fmaf(a.w, w.w, acc[3][3]);
    }
    __syncthreads();
  }
#pragma unroll
  for (int i = 0; i < 4; i++) {
    int m = m0 + ty * 4 + i;
#pragma unroll
    for (int j = 0; j < 4; j++) {
      int n = n0 + tx * 4 + j;
      float v = acc[i][j] + bias[n];
      if (ACT == 1) v = fmaxf(v, 0.f);
      C[(size_t)m * ldc + n] = v;
    }
  }
}

// ---------------- final layer: out[b] = sigmoid(dot(A[b], w) + bias) , K=256 ----------------
__global__ __launch_bounds__(256) void final_kernel(const float* __restrict__ A,
    const float* __restrict__ w, const float* __restrict__ bias, float* __restrict__ out) {
  int row = blockIdx.x * 4 + (threadIdx.x >> 6);
  int lane = threadIdx.x & 63;
  const float4 a = ((const float4*)(A + (size_t)row * 256))[lane];
  const float4 wv = ((const float4*)w)[lane];
  float s = a.x * wv.x + a.y * wv.y + a.z * wv.z + a.w * wv.w;
#pragma unroll
  for (int off = 32; off >= 1; off >>= 1) s += __shfl_xor(s, off);
  if (lane == 0) out[row] = 1.f / (1.f + expf(-(s + bias[0])));
}

extern "C" void kernel_launch(void* const* d_in, const int* in_sizes, int n_in,
                              void* d_out, int out_size, void* d_ws, size_t ws_size,
                              hipStream_t stream) {
  const float* dense_x = (const float*)d_in[0];
  // d_in[1] = lS_o (unused: offsets are implicit arange(B)*P)
  const int* lS_i = (const int*)d_in[2];
  const float* emb = (const float*)d_in[3];
  const float* bw0 = (const float*)d_in[4];
  const float* bb0 = (const float*)d_in[5];
  const float* bw1 = (const float*)d_in[6];
  const float* bb1 = (const float*)d_in[7];
  const float* bw2 = (const float*)d_in[8];
  const float* bb2 = (const float*)d_in[9];
  const float* tw0 = (const float*)d_in[10];
  const float* tb0 = (const float*)d_in[11];
  const float* tw1 = (const float*)d_in[12];
  const float* tb1 = (const float*)d_in[13];
  const float* tw2 = (const float*)d_in[14];
  const float* tb2 = (const float*)d_in[15];
  const float* tw3 = (const float*)d_in[16];
  const float* tb3 = (const float*)d_in[17];
  float* out = (float*)d_out;

  // workspace layout (floats)
  float* ws = (float*)d_ws;
  float* T  = ws;                      // B*27*128 = 56,623,104
  float* x1 = T + (size_t)BATCH * 27 * DIM;     // B*512
  float* x2 = x1 + (size_t)BATCH * 512;         // B*256
  float* R  = x2 + (size_t)BATCH * 256;         // B*479
  float* t1 = R + (size_t)BATCH * 479;          // B*1024
  float* t2 = x1;   // reuse (x1 dead after bottom L1)
  float* t3 = x2;   // reuse (x2 dead after bottom L2)

  const int M = BATCH;

  // bottom MLP
  bot0_kernel<<<BATCH * 2, 256, 0, stream>>>(dense_x, bw0, bb0, x1);
  gemm_wt_kernel<1><<<dim3(256 / 64, M / 64), 256, 0, stream>>>(x1, bw1, bb1, x2, M, 256, 512, 256);
  // bottom out (128) written straight into T[:,0,:] (ldc = 27*128)
  gemm_wt_kernel<1><<<dim3(128 / 64, M / 64), 256, 0, stream>>>(x2, bw2, bb2, T, M, 128, 256, 27 * DIM);

  // embeddings into T[:,1+t,:]
  emb_pool_kernel<<<(NTAB * BATCH) / 8, 256, 0, stream>>>(emb, lS_i, T);

  // interaction -> R = [x, Zflat]
  interact_kernel<<<BATCH, 256, 0, stream>>>(T, R);

  // top MLP
  gemm_wt_kernel<1><<<dim3(1024 / 64, M / 64), 256, 0, stream>>>(R,  tw0, tb0, t1, M, 1024, 479, 1024);
  gemm_wt_kernel<1><<<dim3(512 / 64,  M / 64), 256, 0, stream>>>(t1, tw1, tb1, t2, M, 512, 1024, 512);
  gemm_wt_kernel<1><<<dim3(256 / 64,  M / 64), 256, 0, stream>>>(t2, tw2, tb2, t3, M, 256, 512, 256);
  final_kernel<<<BATCH / 4, 256, 0, stream>>>(t3, tw3, tb3, out);
}

// Round 2
// 959.281 us; speedup vs baseline: 1.0018x; 1.0018x over previous
//
#include <hip/hip_runtime.h>
#include <hip/hip_bf16.h>
#include <math.h>

#define BATCH 16384
#define NTAB 26
#define DIM 128
#define NROWS 100000

// ---------------- bottom layer 0: 13 -> 512, relu ----------------
__global__ __launch_bounds__(256) void bot0_kernel(const float* __restrict__ x,
    const float* __restrict__ W, const float* __restrict__ bias, float* __restrict__ y) {
  int b = blockIdx.x >> 1;
  int m = ((blockIdx.x & 1) << 8) | threadIdx.x;
  const float* xr = x + (size_t)b * 13;
  const float* wr = W + (size_t)m * 13;
  float acc = bias[m];
#pragma unroll
  for (int k = 0; k < 13; k++) acc = fmaf(xr[k], wr[k], acc);
  y[(size_t)b * 512 + m] = fmaxf(acc, 0.f);
}

// ---------------- embedding gather + pool (P=2) into T[:,1+t,:] ----------------
__global__ __launch_bounds__(256) void emb_pool_kernel(const float* __restrict__ tables,
    const int* __restrict__ lS_i, float* __restrict__ T) {
  int q = blockIdx.x * 8 + (threadIdx.x >> 5);   // pair id: t*B + b
  int d4 = threadIdx.x & 31;                     // float4 index within 128-dim row
  int t = q >> 14;                               // B = 16384 = 2^14
  int b = q & 16383;
  const int* idx = lS_i + ((size_t)t << 15) + (b << 1);
  int i0 = idx[0], i1 = idx[1];
  const float4* r0 = (const float4*)(tables + ((size_t)t * NROWS + (size_t)i0) * DIM);
  const float4* r1 = (const float4*)(tables + ((size_t)t * NROWS + (size_t)i1) * DIM);
  float4 v0 = r0[d4], v1 = r1[d4];
  float4 s = make_float4(v0.x + v1.x, v0.y + v1.y, v0.z + v1.z, v0.w + v1.w);
  float4* dst = (float4*)(T + ((size_t)b * 27 + 1 + t) * DIM);
  dst[d4] = s;
}

// ---------------- interaction: R[b] = [x(128), tril(T T^T, k=-1)(351)] ----------------
__global__ __launch_bounds__(256) void interact_kernel(const float* __restrict__ T,
    float* __restrict__ R) {
  int b = blockIdx.x;
  __shared__ float Ts[27 * 133];   // pad stride 133 (gcd(133%32=5,32)=1 spreads banks)
  const float* Tb = T + (size_t)b * (27 * DIM);
  for (int e = threadIdx.x; e < 27 * DIM; e += 256) {
    int r = e >> 7, d = e & 127;
    Ts[r * 133 + d] = Tb[e];
  }
  __syncthreads();
  float* Rb = R + (size_t)b * 479;
  if (threadIdx.x < DIM) Rb[threadIdx.x] = Ts[threadIdx.x];   // x = T row 0
  for (int p = threadIdx.x; p < 351; p += 256) {
    // p -> (i,j), i in 1..26, j<i, row-major tril order
    int i = (int)((sqrtf(8.f * (float)p + 1.f) + 1.f) * 0.5f);
    while (i * (i - 1) / 2 > p) --i;
    while ((i + 1) * i / 2 <= p) ++i;
    int j = p - i * (i - 1) / 2;
    const float* ti = &Ts[i * 133];
    const float* tj = &Ts[j * 133];
    float acc = 0.f;
#pragma unroll 8
    for (int d = 0; d < DIM; d++) acc = fmaf(ti[d], tj[d], acc);
    Rb[DIM + p] = acc;
  }
}

// ---------------- generic tiled fp32 GEMM: C = act(A @ W^T + bias) ----------------
// A: M x K (row-major, lda=K), W: N x K (row-major), C: M x ldc
// 64x64 tile, BK=16, 256 threads, 4x4 per thread
template <int ACT>   // 0 = none, 1 = relu
__global__ __launch_bounds__(256) void gemm_wt_kernel(const float* __restrict__ A,
    const float* __restrict__ W, const float* __restrict__ bias, float* __restrict__ C,
    int M, int N, int K, int ldc) {
  __shared__ float As[16][68];
  __shared__ float Ws[16][68];
  const int tid = threadIdx.x;
  const int tx = tid & 15, ty = tid >> 4;
  const int m0 = blockIdx.y * 64, n0 = blockIdx.x * 64;
  float acc[4][4] = {};
  for (int k0 = 0; k0 < K; k0 += 16) {
#pragma unroll
    for (int i = 0; i < 4; i++) {
      int e = tid + i * 256;
      int row = e >> 4, kk = e & 15;
      int k = k0 + kk;
      As[kk][row] = (k < K) ? A[(size_t)(m0 + row) * K + k] : 0.f;
      Ws[kk][row] = (k < K) ? W[(size_t)(n0 + row) * K + k] : 0.f;
    }
    __syncthreads();
#pragma unroll
    for (int kk = 0; kk < 16; kk++) {
      float4 a = *(const float4*)&As[kk][ty * 4];
      float4 w = *(const float4*)&Ws[kk][tx * 4];
      acc[0][0] = fmaf(a.x, w.x, acc[0][0]);
      acc[0][1] = fmaf(a.x, w.y, acc[0][1]);
      acc[0][2] = fmaf(a.x, w.z, acc[0][2]);
      acc[0][3] = fmaf(a.x, w.w, acc[0][3]);
      acc[1][0] = fmaf(a.y, w.x, acc[1][0]);
      acc[1][1] = fmaf(a.y, w.y, acc[1][1]);
      acc[1][2] = fmaf(a.y, w.z, acc[1][2]);
      acc[1][3] = fmaf(a.y, w.w, acc[1][3]);
      acc[2][0] = fmaf(a.z, w.x, acc[2][0]);
      acc[2][1] = fmaf(a.z, w.y, acc[2][1]);
      acc[2][2] = fmaf(a.z, w.z, acc[2][2]);
      acc[2][3] = fmaf(a.z, w.w, acc[2][3]);
      acc[3][0] = fmaf(a.w, w.x, acc[3][0]);
      acc[3][1] = fmaf(a.w, w.y, acc[3][1]);
      acc[3][2] = fmaf(a.w, w.z, acc[3][2]);
      acc[3][3] = fmaf(a.w, w.w, acc[3][3]);
    }
    __syncthreads();
  }
#pragma unroll
  for (int i = 0; i < 4; i++) {
    int m = m0 + ty * 4 + i;
#pragma unroll
    for (int j = 0; j < 4; j++) {
      int n = n0 + tx * 4 + j;
      float v = acc[i][j] + bias[n];
      if (ACT == 1) v = fmaxf(v, 0.f);
      C[(size_t)m * ldc + n] = v;
    }
  }
}

// ---------------- final layer: out[b] = sigmoid(dot(A[b], w) + bias) , K=256 ----------------
__global__ __launch_bounds__(256) void final_kernel(const float* __restrict__ A,
    const float* __restrict__ w, const float* __restrict__ bias, float* __restrict__ out) {
  int row = blockIdx.x * 4 + (threadIdx.x >> 6);
  int lane = threadIdx.x & 63;
  const float4 a = ((const float4*)(A + (size_t)row * 256))[lane];
  const float4 wv = ((const float4*)w)[lane];
  float s = a.x * wv.x + a.y * wv.y + a.z * wv.z + a.w * wv.w;
#pragma unroll
  for (int off = 32; off >= 1; off >>= 1) s += __shfl_xor(s, off);
  if (lane == 0) out[row] = 1.f / (1.f + expf(-(s + bias[0])));
}

extern "C" void kernel_launch(void* const* d_in, const int* in_sizes, int n_in,
                              void* d_out, int out_size, void* d_ws, size_t ws_size,
                              hipStream_t stream) {
  const float* dense_x = (const float*)d_in[0];
  // d_in[1] = lS_o (unused: offsets are implicit arange(B)*P)
  const int* lS_i = (const int*)d_in[2];
  const float* emb = (const float*)d_in[3];
  const float* bw0 = (const float*)d_in[4];
  const float* bb0 = (const float*)d_in[5];
  const float* bw1 = (const float*)d_in[6];
  const float* bb1 = (const float*)d_in[7];
  const float* bw2 = (const float*)d_in[8];
  const float* bb2 = (const float*)d_in[9];
  const float* tw0 = (const float*)d_in[10];
  const float* tb0 = (const float*)d_in[11];
  const float* tw1 = (const float*)d_in[12];
  const float* tb1 = (const float*)d_in[13];
  const float* tw2 = (const float*)d_in[14];
  const float* tb2 = (const float*)d_in[15];
  const float* tw3 = (const float*)d_in[16];
  const float* tb3 = (const float*)d_in[17];
  float* out = (float*)d_out;

  // workspace layout (floats)
  float* ws = (float*)d_ws;
  float* T  = ws;                      // B*27*128 = 56,623,104
  float* x1 = T + (size_t)BATCH * 27 * DIM;     // B*512
  float* x2 = x1 + (size_t)BATCH * 512;         // B*256
  float* R  = x2 + (size_t)BATCH * 256;         // B*479
  float* t1 = R + (size_t)BATCH * 479;          // B*1024
  float* t2 = x1;   // reuse (x1 dead after bottom L1)
  float* t3 = x2;   // reuse (x2 dead after bottom L2)

  const int M = BATCH;

  // bottom MLP
  bot0_kernel<<<BATCH * 2, 256, 0, stream>>>(dense_x, bw0, bb0, x1);
  gemm_wt_kernel<1><<<dim3(256 / 64, M / 64), 256, 0, stream>>>(x1, bw1, bb1, x2, M, 256, 512, 256);
  // bottom out (128) written straight into T[:,0,:] (ldc = 27*128)
  gemm_wt_kernel<1><<<dim3(128 / 64, M / 64), 256, 0, stream>>>(x2, bw2, bb2, T, M, 128, 256, 27 * DIM);

  // embeddings into T[:,1+t,:]
  emb_pool_kernel<<<(NTAB * BATCH) / 8, 256, 0, stream>>>(emb, lS_i, T);

  // interaction -> R = [x, Zflat]
  interact_kernel<<<BATCH, 256, 0, stream>>>(T, R);

  // top MLP
  gemm_wt_kernel<1><<<dim3(1024 / 64, M / 64), 256, 0, stream>>>(R,  tw0, tb0, t1, M, 1024, 479, 1024);
  gemm_wt_kernel<1><<<dim3(512 / 64,  M / 64), 256, 0, stream>>>(t1, tw1, tb1, t2, M, 512, 1024, 512);
  gemm_wt_kernel<1><<<dim3(256 / 64,  M / 64), 256, 0, stream>>>(t2, tw2, tb2, t3, M, 256, 512, 256);
  final_kernel<<<BATCH / 4, 256, 0, stream>>>(t3, tw3, tb3, out);
}

// Round 3
// 368.548 us; speedup vs baseline: 2.6076x; 2.6029x over previous
//
#include <hip/hip_runtime.h>
#include <hip/hip_bf16.h>
#include <math.h>

#define BATCH 16384
#define NTAB 26
#define DIM 128
#define NROWS 100000

typedef short bf16x8 __attribute__((ext_vector_type(8)));
typedef float f32x4 __attribute__((ext_vector_type(4)));

__device__ __forceinline__ ushort f2b(float f) {   // fp32 -> bf16 RNE
  union { float f; unsigned u; } c; c.f = f;
  unsigned r = (c.u + 0x7fffu + ((c.u >> 16) & 1u)) >> 16;
  return (ushort)r;
}
__device__ __forceinline__ float b2f(ushort u) {
  union { unsigned u; float f; } c; c.u = (unsigned)u << 16;
  return c.f;
}

__device__ __forceinline__ void gload_lds16(const void* g, void* l) {
  __builtin_amdgcn_global_load_lds(
      (const __attribute__((address_space(1))) void*)g,
      (__attribute__((address_space(3))) void*)l, 16, 0, 0);
}

// ---------------- weight fp32 -> bf16 conversion ----------------
__global__ __launch_bounds__(256) void cvt_bf16_kernel(const float* __restrict__ in,
    ushort* __restrict__ out, int n) {
  int i = blockIdx.x * 256 + threadIdx.x;
  if (i < n) out[i] = f2b(in[i]);
}
// pad K (479) -> KP (512) with zeros
__global__ __launch_bounds__(256) void cvt_bf16_pad_kernel(const float* __restrict__ in,
    ushort* __restrict__ out, int K, int KP, int total) {
  int i = blockIdx.x * 256 + threadIdx.x;
  if (i < total) {
    int r = i / KP, c = i - r * KP;
    out[i] = (c < K) ? f2b(in[(size_t)r * K + c]) : (ushort)0;
  }
}

// ---------------- bottom layer 0: 13 -> 512, relu, bf16 out ----------------
__global__ __launch_bounds__(256) void bot0_kernel(const float* __restrict__ x,
    const float* __restrict__ W, const float* __restrict__ bias, ushort* __restrict__ y) {
  int b = blockIdx.x >> 1;
  int m = ((blockIdx.x & 1) << 8) | threadIdx.x;
  const float* xr = x + (size_t)b * 13;
  const float* wr = W + (size_t)m * 13;
  float acc = bias[m];
#pragma unroll
  for (int k = 0; k < 13; k++) acc = fmaf(xr[k], wr[k], acc);
  y[(size_t)b * 512 + m] = f2b(fmaxf(acc, 0.f));
}

// ---------------- embedding gather + pool (P=2) into T[:,1+t,:], bf16 out ----------------
__global__ __launch_bounds__(256) void emb_pool_kernel(const float* __restrict__ tables,
    const int* __restrict__ lS_i, ushort* __restrict__ T) {
  int q = blockIdx.x * 8 + (threadIdx.x >> 5);   // pair id: t*B + b
  int d4 = threadIdx.x & 31;                     // float4 index within 128-dim row
  int t = q >> 14;                               // B = 16384 = 2^14
  int b = q & 16383;
  const int* idx = lS_i + ((size_t)t << 15) + (b << 1);
  int i0 = idx[0], i1 = idx[1];
  const float4* r0 = (const float4*)(tables + ((size_t)t * NROWS + (size_t)i0) * DIM);
  const float4* r1 = (const float4*)(tables + ((size_t)t * NROWS + (size_t)i1) * DIM);
  float4 v0 = r0[d4], v1 = r1[d4];
  ushort4 s;
  s.x = f2b(v0.x + v1.x); s.y = f2b(v0.y + v1.y);
  s.z = f2b(v0.z + v1.z); s.w = f2b(v0.w + v1.w);
  *(ushort4*)(T + ((size_t)b * 27 + 1 + t) * DIM + d4 * 4) = s;
}

// ---------------- interaction: R[b] = [x(128) | tril(T T^T)(351) | 0-pad(33)] bf16 ----------------
__global__ __launch_bounds__(256) void interact_kernel(const ushort* __restrict__ T,
    ushort* __restrict__ R) {
  int b = blockIdx.x;
  __shared__ float Ts[27 * 133];
  const ushort* Tb = T + (size_t)b * (27 * DIM);
  for (int e = threadIdx.x; e < 27 * DIM; e += 256) {
    int r = e >> 7, d = e & 127;
    Ts[r * 133 + d] = b2f(Tb[e]);
  }
  __syncthreads();
  ushort* Rb = R + (size_t)b * 512;
  if (threadIdx.x < DIM) Rb[threadIdx.x] = Tb[threadIdx.x];       // x row (already bf16)
  for (int c = 479 + threadIdx.x; c < 512; c += 256) Rb[c] = 0;   // K padding
  for (int p = threadIdx.x; p < 351; p += 256) {
    int i = (int)((sqrtf(8.f * (float)p + 1.f) + 1.f) * 0.5f);
    while (i * (i - 1) / 2 > p) --i;
    while ((i + 1) * i / 2 <= p) ++i;
    int j = p - i * (i - 1) / 2;
    const float* ti = &Ts[i * 133];
    const float* tj = &Ts[j * 133];
    float acc = 0.f;
#pragma unroll 8
    for (int d = 0; d < DIM; d++) acc = fmaf(ti[d], tj[d], acc);
    Rb[DIM + p] = f2b(acc);
  }
}

// ---------------- bf16 MFMA GEMM: C = act(A @ W^T + bias), m97 structure ----------------
// A: M x K bf16 (row-major, packed), W: N x K bf16, C: M x ldc bf16
// 128x128 tile, BK=32, 256 threads = 4 waves (2x2 of 64x64), 4x4 MFMA frags/wave
template <int ACT>   // 0 = none, 1 = relu
__global__ __launch_bounds__(256) void gemm_bf16_kernel(
    const ushort* __restrict__ A, const ushort* __restrict__ W,
    const float* __restrict__ bias, ushort* __restrict__ C, int K, int ldc) {
  __shared__ ushort As[128 * 32];
  __shared__ ushort Bs[128 * 32];
  const int tid = threadIdx.x;
  const int lane = tid & 63, wave = tid >> 6;
  const int m0 = blockIdx.y * 128, n0 = blockIdx.x * 128;
  const int wr = wave >> 1, wc = wave & 1;           // 64x64 wave sub-tile

  // staging: lane covers row = lane>>2 within 16-row group, kpart = (lane&3)*8
  const int srow = lane >> 2;
  const int skp = (lane & 3) * 8;
  const ushort* Ag = A + (size_t)(m0 + wave * 16 + srow) * K + skp;
  const ushort* Wg = W + (size_t)(n0 + wave * 16 + srow) * K + skp;
  ushort* AsW = &As[(wave * 16) * 32];
  ushort* BsW = &Bs[(wave * 16) * 32];

  f32x4 acc[4][4] = {};
  const int fr = lane & 15;          // fragment row
  const int fk = (lane >> 4) * 8;    // fragment k offset

  for (int k0 = 0; k0 < K; k0 += 32) {
    gload_lds16(Ag + k0, AsW);
    gload_lds16(Ag + (size_t)64 * K + k0, AsW + 64 * 32);
    gload_lds16(Wg + k0, BsW);
    gload_lds16(Wg + (size_t)64 * K + k0, BsW + 64 * 32);
    __syncthreads();
    bf16x8 a[4], b[4];
#pragma unroll
    for (int i = 0; i < 4; i++) {
      a[i] = *(const bf16x8*)&As[(wr * 64 + i * 16 + fr) * 32 + fk];
      b[i] = *(const bf16x8*)&Bs[(wc * 64 + i * 16 + fr) * 32 + fk];
    }
#pragma unroll
    for (int i = 0; i < 4; i++)
#pragma unroll
      for (int j = 0; j < 4; j++)
        acc[i][j] = __builtin_amdgcn_mfma_f32_16x16x32_bf16(a[i], b[j], acc[i][j], 0, 0, 0);
    __syncthreads();
  }

  // epilogue: C/D layout col=lane&15, row=(lane>>4)*4+reg  [m89-verified]
  const int col_l = lane & 15, row_h = (lane >> 4) * 4;
#pragma unroll
  for (int j = 0; j < 4; j++) {
    int n = n0 + wc * 64 + j * 16 + col_l;
    float bs = bias[n];
#pragma unroll
    for (int i = 0; i < 4; i++) {
      int mbase = m0 + wr * 64 + i * 16 + row_h;
#pragma unroll
      for (int r = 0; r < 4; r++) {
        float v = acc[i][j][r] + bs;
        if (ACT) v = fmaxf(v, 0.f);
        C[(size_t)(mbase + r) * ldc + n] = f2b(v);
      }
    }
  }
}

// ---------------- final layer: out[b] = sigmoid(dot(A[b], w) + bias), K=256 bf16 in ----------------
__global__ __launch_bounds__(256) void final_kernel(const ushort* __restrict__ A,
    const float* __restrict__ w, const float* __restrict__ bias, float* __restrict__ out) {
  int row = blockIdx.x * 4 + (threadIdx.x >> 6);
  int lane = threadIdx.x & 63;
  ushort4 a4 = ((const ushort4*)(A + (size_t)row * 256))[lane];
  float4 wv = ((const float4*)w)[lane];
  float s = b2f(a4.x) * wv.x + b2f(a4.y) * wv.y + b2f(a4.z) * wv.z + b2f(a4.w) * wv.w;
#pragma unroll
  for (int off = 32; off >= 1; off >>= 1) s += __shfl_xor(s, off);
  if (lane == 0) out[row] = 1.f / (1.f + expf(-(s + bias[0])));
}

extern "C" void kernel_launch(void* const* d_in, const int* in_sizes, int n_in,
                              void* d_out, int out_size, void* d_ws, size_t ws_size,
                              hipStream_t stream) {
  const float* dense_x = (const float*)d_in[0];
  const int* lS_i = (const int*)d_in[2];
  const float* emb = (const float*)d_in[3];
  const float* bw0 = (const float*)d_in[4];
  const float* bb0 = (const float*)d_in[5];
  const float* bw1 = (const float*)d_in[6];
  const float* bb1 = (const float*)d_in[7];
  const float* bw2 = (const float*)d_in[8];
  const float* bb2 = (const float*)d_in[9];
  const float* tw0 = (const float*)d_in[10];
  const float* tb0 = (const float*)d_in[11];
  const float* tw1 = (const float*)d_in[12];
  const float* tb1 = (const float*)d_in[13];
  const float* tw2 = (const float*)d_in[14];
  const float* tb2 = (const float*)d_in[15];
  const float* tw3 = (const float*)d_in[16];
  const float* tb3 = (const float*)d_in[17];
  float* out = (float*)d_out;

  // workspace layout (bf16 activations)
  char* w = (char*)d_ws;
  ushort* Tb  = (ushort*)w; w += (size_t)BATCH * 27 * DIM * 2;   // 113 MB
  ushort* x1  = (ushort*)w; w += (size_t)BATCH * 512 * 2;
  ushort* x2  = (ushort*)w; w += (size_t)BATCH * 256 * 2;
  ushort* R   = (ushort*)w; w += (size_t)BATCH * 512 * 2;
  ushort* t1  = (ushort*)w; w += (size_t)BATCH * 1024 * 2;
  ushort* wb1 = (ushort*)w; w += 256 * 512 * 2;
  ushort* wb2 = (ushort*)w; w += 128 * 256 * 2;
  ushort* wt0 = (ushort*)w; w += 1024 * 512 * 2;
  ushort* wt1 = (ushort*)w; w += 512 * 1024 * 2;
  ushort* wt2 = (ushort*)w; w += 256 * 512 * 2;
  ushort* t2 = x1;   // reuse (x1 dead after bottom L1)
  ushort* t3 = x2;   // reuse (x2 dead after bottom L2)

  // weight conversions (independent, tiny)
  cvt_bf16_kernel<<<(256 * 512 + 255) / 256, 256, 0, stream>>>(bw1, wb1, 256 * 512);
  cvt_bf16_kernel<<<(128 * 256 + 255) / 256, 256, 0, stream>>>(bw2, wb2, 128 * 256);
  cvt_bf16_pad_kernel<<<(1024 * 512 + 255) / 256, 256, 0, stream>>>(tw0, wt0, 479, 512, 1024 * 512);
  cvt_bf16_kernel<<<(512 * 1024 + 255) / 256, 256, 0, stream>>>(tw1, wt1, 512 * 1024);
  cvt_bf16_kernel<<<(256 * 512 + 255) / 256, 256, 0, stream>>>(tw2, wt2, 256 * 512);

  // bottom MLP
  bot0_kernel<<<BATCH * 2, 256, 0, stream>>>(dense_x, bw0, bb0, x1);
  gemm_bf16_kernel<1><<<dim3(256 / 128, BATCH / 128), 256, 0, stream>>>(x1, wb1, bb1, x2, 512, 256);
  gemm_bf16_kernel<1><<<dim3(128 / 128, BATCH / 128), 256, 0, stream>>>(x2, wb2, bb2, Tb, 256, 27 * DIM);

  // embeddings into T[:,1+t,:]
  emb_pool_kernel<<<(NTAB * BATCH) / 8, 256, 0, stream>>>(emb, lS_i, Tb);

  // interaction -> R = [x | Zflat | 0pad] (stride 512)
  interact_kernel<<<BATCH, 256, 0, stream>>>(Tb, R);

  // top MLP
  gemm_bf16_kernel<1><<<dim3(1024 / 128, BATCH / 128), 256, 0, stream>>>(R,  wt0, tb0, t1, 512, 1024);
  gemm_bf16_kernel<1><<<dim3(512 / 128,  BATCH / 128), 256, 0, stream>>>(t1, wt1, tb1, t2, 1024, 512);
  gemm_bf16_kernel<1><<<dim3(256 / 128,  BATCH / 128), 256, 0, stream>>>(t2, wt2, tb2, t3, 512, 256);
  final_kernel<<<BATCH / 4, 256, 0, stream>>>(t3, tw3, tb3, out);
}

// Round 4
// 241.694 us; speedup vs baseline: 3.9762x; 1.5249x over previous
//
#include <hip/hip_runtime.h>
#include <hip/hip_bf16.h>
#include <math.h>

#define BATCH 16384
#define NTAB 26
#define DIM 128
#define NROWS 100000

typedef short bf16x8 __attribute__((ext_vector_type(8)));
typedef float f32x4 __attribute__((ext_vector_type(4)));
typedef float f32x16 __attribute__((ext_vector_type(16)));

__device__ __forceinline__ ushort f2b(float f) {   // fp32 -> bf16 RNE
  union { float f; unsigned u; } c; c.f = f;
  unsigned r = (c.u + 0x7fffu + ((c.u >> 16) & 1u)) >> 16;
  return (ushort)r;
}
__device__ __forceinline__ float b2f(ushort u) {
  union { unsigned u; float f; } c; c.u = (unsigned)u << 16;
  return c.f;
}

__device__ __forceinline__ void gload_lds16(const void* g, void* l) {
  __builtin_amdgcn_global_load_lds(
      (const __attribute__((address_space(1))) void*)g,
      (__attribute__((address_space(3))) void*)l, 16, 0, 0);
}

// ---------------- all weight fp32 -> bf16 conversions, one launch ----------------
__global__ __launch_bounds__(256) void cvt_all_kernel(
    const float* __restrict__ bw1, const float* __restrict__ bw2,
    const float* __restrict__ tw0, const float* __restrict__ tw1,
    const float* __restrict__ tw2,
    ushort* __restrict__ o1, ushort* __restrict__ o2, ushort* __restrict__ o3,
    ushort* __restrict__ o4, ushort* __restrict__ o5) {
  int i = blockIdx.x * 256 + threadIdx.x;
  switch (blockIdx.y) {
    case 0: if (i < 256 * 512) o1[i] = f2b(bw1[i]); break;
    case 1: if (i < 128 * 256) o2[i] = f2b(bw2[i]); break;
    case 2: if (i < 1024 * 512) {            // pad K 479 -> 512
      int r = i >> 9, c = i & 511;
      o3[i] = (c < 479) ? f2b(tw0[(size_t)r * 479 + c]) : (ushort)0;
    } break;
    case 3: if (i < 512 * 1024) o4[i] = f2b(tw1[i]); break;
    case 4: if (i < 256 * 512) o5[i] = f2b(tw2[i]); break;
  }
}

// ---------------- bottom layer 0: 13 -> 512, relu, bf16 out ----------------
__global__ __launch_bounds__(256) void bot0_kernel(const float* __restrict__ x,
    const float* __restrict__ W, const float* __restrict__ bias, ushort* __restrict__ y) {
  int b = blockIdx.x >> 1;
  int m = ((blockIdx.x & 1) << 8) | threadIdx.x;
  const float* xr = x + (size_t)b * 13;
  const float* wr = W + (size_t)m * 13;
  float acc = bias[m];
#pragma unroll
  for (int k = 0; k < 13; k++) acc = fmaf(xr[k], wr[k], acc);
  y[(size_t)b * 512 + m] = f2b(fmaxf(acc, 0.f));
}

// ---------------- fused embedding gather+pool+interaction ----------------
// 4 waves/block, 1 batch row per wave. Per wave:
//  - stage [32][128] bf16 tile in LDS (row0 = x, rows 1..26 = pooled tables, 27..31 = 0)
//    with XOR swizzle byte ^= ((row&7)<<4)
//  - Z = T T^T via 8x mfma_f32_32x32x16_bf16, A-frag == B-frag (symmetric)
//  - write R[b] = [x(128) | tril(Z)(351) | zeros(33)] bf16, stride 512
__global__ __launch_bounds__(256) void embint_kernel(
    const float* __restrict__ tables, const int* __restrict__ lS_i,
    const ushort* __restrict__ xb, ushort* __restrict__ R) {
  __shared__ ushort Tls[4][32 * 128];          // 8 KB per wave
  const int wave = threadIdx.x >> 6, lane = threadIdx.x & 63;
  const int b = blockIdx.x * 4 + wave;
  char* tl = (char*)Tls[wave];

  // row 0 = x (swz for row 0 is identity)
  *(uint*)(tl + lane * 4) = *(const uint*)(xb + (size_t)b * 128 + lane * 2);
  // rows 27..31 = 0
#pragma unroll
  for (int r = 27; r < 32; r++)
    *(uint*)(tl + r * 256 + ((lane * 4) ^ ((r & 7) << 4))) = 0;
  // rows 1..26 = pooled embeddings (P=2)
#pragma unroll 4
  for (int t = 0; t < NTAB; t++) {
    const int* idx = lS_i + ((size_t)t << 15) + (b << 1);
    int i0 = idx[0], i1 = idx[1];
    float2 v0 = ((const float2*)(tables + ((size_t)t * NROWS + i0) * DIM))[lane];
    float2 v1 = ((const float2*)(tables + ((size_t)t * NROWS + i1) * DIM))[lane];
    ushort2 s; s.x = f2b(v0.x + v1.x); s.y = f2b(v0.y + v1.y);
    int row = t + 1;
    *(uint*)(tl + row * 256 + ((lane * 4) ^ ((row & 7) << 4))) = *(uint*)&s;
  }
  __syncthreads();

  // fragments: lane holds row = lane&31, k = (lane>>5)*8 + r within each K=16 step
  const int row = lane & 31;
  const int khb = (lane >> 5) * 16;            // byte offset of k-half
  const int swz = (row & 7) << 4;
  f32x16 z = {};
#pragma unroll
  for (int ks = 0; ks < 8; ks++) {
    bf16x8 a = *(const bf16x8*)(tl + row * 256 + ((ks * 32 + khb) ^ swz));
    z = __builtin_amdgcn_mfma_f32_32x32x16_bf16(a, a, z, 0, 0, 0);
  }

  ushort* Rb = R + (size_t)b * 512;
  // x copy (row0 is linear in LDS)
  *(uint*)(Rb + lane * 2) = *(const uint*)(tl + lane * 4);
  // K padding 479..511
  if (lane < 33) Rb[479 + lane] = 0;
  // tril(Z, k=-1): C/D layout col=lane&31, row=(reg&3)+8*(reg>>2)+4*(lane>>5)
  const int j = lane & 31;
  const int rb4 = (lane >> 5) * 4;
#pragma unroll
  for (int r = 0; r < 16; r++) {
    int i = (r & 3) + 8 * (r >> 2) + rb4;
    if (i <= 26 && j < i) Rb[DIM + (i * (i - 1)) / 2 + j] = f2b(z[r]);
  }
}

// ---------------- bf16 MFMA GEMM: C = act(A @ W^T + bias), m97 structure ----------------
// 128x128 tile, BK=32, 256 threads = 4 waves (2x2 of 64x64), 4x4 MFMA frags/wave
template <int ACT>   // 0 = none, 1 = relu
__global__ __launch_bounds__(256) void gemm_bf16_kernel(
    const ushort* __restrict__ A, const ushort* __restrict__ W,
    const float* __restrict__ bias, ushort* __restrict__ C, int K, int ldc) {
  __shared__ ushort As[128 * 32];
  __shared__ ushort Bs[128 * 32];
  const int tid = threadIdx.x;
  const int lane = tid & 63, wave = tid >> 6;
  const int m0 = blockIdx.y * 128, n0 = blockIdx.x * 128;
  const int wr = wave >> 1, wc = wave & 1;

  const int srow = lane >> 2;
  const int skp = (lane & 3) * 8;
  const ushort* Ag = A + (size_t)(m0 + wave * 16 + srow) * K + skp;
  const ushort* Wg = W + (size_t)(n0 + wave * 16 + srow) * K + skp;
  ushort* AsW = &As[(wave * 16) * 32];
  ushort* BsW = &Bs[(wave * 16) * 32];

  f32x4 acc[4][4] = {};
  const int fr = lane & 15;
  const int fk = (lane >> 4) * 8;

  for (int k0 = 0; k0 < K; k0 += 32) {
    gload_lds16(Ag + k0, AsW);
    gload_lds16(Ag + (size_t)64 * K + k0, AsW + 64 * 32);
    gload_lds16(Wg + k0, BsW);
    gload_lds16(Wg + (size_t)64 * K + k0, BsW + 64 * 32);
    __syncthreads();
    bf16x8 a[4], b[4];
#pragma unroll
    for (int i = 0; i < 4; i++) {
      a[i] = *(const bf16x8*)&As[(wr * 64 + i * 16 + fr) * 32 + fk];
      b[i] = *(const bf16x8*)&Bs[(wc * 64 + i * 16 + fr) * 32 + fk];
    }
#pragma unroll
    for (int i = 0; i < 4; i++)
#pragma unroll
      for (int j = 0; j < 4; j++)
        acc[i][j] = __builtin_amdgcn_mfma_f32_16x16x32_bf16(a[i], b[j], acc[i][j], 0, 0, 0);
    __syncthreads();
  }

  const int col_l = lane & 15, row_h = (lane >> 4) * 4;
#pragma unroll
  for (int j = 0; j < 4; j++) {
    int n = n0 + wc * 64 + j * 16 + col_l;
    float bs = bias[n];
#pragma unroll
    for (int i = 0; i < 4; i++) {
      int mbase = m0 + wr * 64 + i * 16 + row_h;
#pragma unroll
      for (int r = 0; r < 4; r++) {
        float v = acc[i][j][r] + bs;
        if (ACT) v = fmaxf(v, 0.f);
        C[(size_t)(mbase + r) * ldc + n] = f2b(v);
      }
    }
  }
}

// ---------------- final layer: out[b] = sigmoid(dot(A[b], w) + bias), K=256 bf16 in ----------------
__global__ __launch_bounds__(256) void final_kernel(const ushort* __restrict__ A,
    const float* __restrict__ w, const float* __restrict__ bias, float* __restrict__ out) {
  int row = blockIdx.x * 4 + (threadIdx.x >> 6);
  int lane = threadIdx.x & 63;
  ushort4 a4 = ((const ushort4*)(A + (size_t)row * 256))[lane];
  float4 wv = ((const float4*)w)[lane];
  float s = b2f(a4.x) * wv.x + b2f(a4.y) * wv.y + b2f(a4.z) * wv.z + b2f(a4.w) * wv.w;
#pragma unroll
  for (int off = 32; off >= 1; off >>= 1) s += __shfl_xor(s, off);
  if (lane == 0) out[row] = 1.f / (1.f + expf(-(s + bias[0])));
}

extern "C" void kernel_launch(void* const* d_in, const int* in_sizes, int n_in,
                              void* d_out, int out_size, void* d_ws, size_t ws_size,
                              hipStream_t stream) {
  const float* dense_x = (const float*)d_in[0];
  const int* lS_i = (const int*)d_in[2];
  const float* emb = (const float*)d_in[3];
  const float* bw0 = (const float*)d_in[4];
  const float* bb0 = (const float*)d_in[5];
  const float* bw1 = (const float*)d_in[6];
  const float* bb1 = (const float*)d_in[7];
  const float* bw2 = (const float*)d_in[8];
  const float* bb2 = (const float*)d_in[9];
  const float* tw0 = (const float*)d_in[10];
  const float* tb0 = (const float*)d_in[11];
  const float* tw1 = (const float*)d_in[12];
  const float* tb1 = (const float*)d_in[13];
  const float* tw2 = (const float*)d_in[14];
  const float* tb2 = (const float*)d_in[15];
  const float* tw3 = (const float*)d_in[16];
  const float* tb3 = (const float*)d_in[17];
  float* out = (float*)d_out;

  // workspace layout (bf16)
  char* w = (char*)d_ws;
  ushort* xb  = (ushort*)w; w += (size_t)BATCH * 128 * 2;    // bottom MLP output
  ushort* x1  = (ushort*)w; w += (size_t)BATCH * 512 * 2;
  ushort* x2  = (ushort*)w; w += (size_t)BATCH * 256 * 2;
  ushort* R   = (ushort*)w; w += (size_t)BATCH * 512 * 2;
  ushort* t1  = (ushort*)w; w += (size_t)BATCH * 1024 * 2;
  ushort* wb1 = (ushort*)w; w += 256 * 512 * 2;
  ushort* wb2 = (ushort*)w; w += 128 * 256 * 2;
  ushort* wt0 = (ushort*)w; w += 1024 * 512 * 2;
  ushort* wt1 = (ushort*)w; w += 512 * 1024 * 2;
  ushort* wt2 = (ushort*)w; w += 256 * 512 * 2;
  ushort* t2 = x1;   // reuse
  ushort* t3 = x2;   // reuse

  // all weight conversions in one launch
  cvt_all_kernel<<<dim3(2048, 5), 256, 0, stream>>>(bw1, bw2, tw0, tw1, tw2,
                                                    wb1, wb2, wt0, wt1, wt2);

  // bottom MLP -> xb (packed B x 128)
  bot0_kernel<<<BATCH * 2, 256, 0, stream>>>(dense_x, bw0, bb0, x1);
  gemm_bf16_kernel<1><<<dim3(256 / 128, BATCH / 128), 256, 0, stream>>>(x1, wb1, bb1, x2, 512, 256);
  gemm_bf16_kernel<1><<<dim3(1, BATCH / 128), 256, 0, stream>>>(x2, wb2, bb2, xb, 256, 128);

  // fused embeddings + interaction -> R = [x | tril(Z) | 0pad]
  embint_kernel<<<BATCH / 4, 256, 0, stream>>>(emb, lS_i, xb, R);

  // top MLP
  gemm_bf16_kernel<1><<<dim3(1024 / 128, BATCH / 128), 256, 0, stream>>>(R,  wt0, tb0, t1, 512, 1024);
  gemm_bf16_kernel<1><<<dim3(512 / 128,  BATCH / 128), 256, 0, stream>>>(t1, wt1, tb1, t2, 1024, 512);
  gemm_bf16_kernel<1><<<dim3(256 / 128,  BATCH / 128), 256, 0, stream>>>(t2, wt2, tb2, t3, 512, 256);
  final_kernel<<<BATCH / 4, 256, 0, stream>>>(t3, tw3, tb3, out);
}

// Round 5
// 226.220 us; speedup vs baseline: 4.2482x; 1.0684x over previous
//
#include <hip/hip_runtime.h>
#include <hip/hip_bf16.h>
#include <math.h>

#define BATCH 16384
#define NTAB 26
#define DIM 128
#define NROWS 100000

typedef short bf16x8 __attribute__((ext_vector_type(8)));
typedef float f32x4 __attribute__((ext_vector_type(4)));
typedef float f32x16 __attribute__((ext_vector_type(16)));

__device__ __forceinline__ ushort f2b(float f) {   // fp32 -> bf16 RNE
  union { float f; unsigned u; } c; c.f = f;
  unsigned r = (c.u + 0x7fffu + ((c.u >> 16) & 1u)) >> 16;
  return (ushort)r;
}
__device__ __forceinline__ float b2f(ushort u) {
  union { unsigned u; float f; } c; c.u = (unsigned)u << 16;
  return c.f;
}

__device__ __forceinline__ void gload_lds16(const void* g, void* l) {
  __builtin_amdgcn_global_load_lds(
      (const __attribute__((address_space(1))) void*)g,
      (__attribute__((address_space(3))) void*)l, 16, 0, 0);
}

// ---------------- all weight fp32 -> bf16 conversions, one launch ----------------
__global__ __launch_bounds__(256) void cvt_all_kernel(
    const float* __restrict__ bw1, const float* __restrict__ bw2,
    const float* __restrict__ tw0, const float* __restrict__ tw1,
    const float* __restrict__ tw2,
    ushort* __restrict__ o1, ushort* __restrict__ o2, ushort* __restrict__ o3,
    ushort* __restrict__ o4, ushort* __restrict__ o5) {
  int i = blockIdx.x * 256 + threadIdx.x;
  switch (blockIdx.y) {
    case 0: if (i < 256 * 512) o1[i] = f2b(bw1[i]); break;
    case 1: if (i < 128 * 256) o2[i] = f2b(bw2[i]); break;
    case 2: if (i < 1024 * 512) {            // pad K 479 -> 512
      int r = i >> 9, c = i & 511;
      o3[i] = (c < 479) ? f2b(tw0[(size_t)r * 479 + c]) : (ushort)0;
    } break;
    case 3: if (i < 512 * 1024) o4[i] = f2b(tw1[i]); break;
    case 4: if (i < 256 * 512) o5[i] = f2b(tw2[i]); break;
  }
}

// ---------------- bottom layer 0: 13 -> 512, relu, bf16 out ----------------
__global__ __launch_bounds__(256) void bot0_kernel(const float* __restrict__ x,
    const float* __restrict__ W, const float* __restrict__ bias, ushort* __restrict__ y) {
  int b = blockIdx.x >> 1;
  int m = ((blockIdx.x & 1) << 8) | threadIdx.x;
  const float* xr = x + (size_t)b * 13;
  const float* wr = W + (size_t)m * 13;
  float acc = bias[m];
#pragma unroll
  for (int k = 0; k < 13; k++) acc = fmaf(xr[k], wr[k], acc);
  y[(size_t)b * 512 + m] = f2b(fmaxf(acc, 0.f));
}

// ---------------- fused embedding gather+pool+interaction ----------------
__global__ __launch_bounds__(256) void embint_kernel(
    const float* __restrict__ tables, const int* __restrict__ lS_i,
    const ushort* __restrict__ xb, ushort* __restrict__ R) {
  __shared__ ushort Tls[4][32 * 128];          // 8 KB per wave
  const int wave = threadIdx.x >> 6, lane = threadIdx.x & 63;
  const int b = blockIdx.x * 4 + wave;
  char* tl = (char*)Tls[wave];

  *(uint*)(tl + lane * 4) = *(const uint*)(xb + (size_t)b * 128 + lane * 2);
#pragma unroll
  for (int r = 27; r < 32; r++)
    *(uint*)(tl + r * 256 + ((lane * 4) ^ ((r & 7) << 4))) = 0;
#pragma unroll 4
  for (int t = 0; t < NTAB; t++) {
    const int* idx = lS_i + ((size_t)t << 15) + (b << 1);
    int i0 = idx[0], i1 = idx[1];
    float2 v0 = ((const float2*)(tables + ((size_t)t * NROWS + i0) * DIM))[lane];
    float2 v1 = ((const float2*)(tables + ((size_t)t * NROWS + i1) * DIM))[lane];
    ushort2 s; s.x = f2b(v0.x + v1.x); s.y = f2b(v0.y + v1.y);
    int row = t + 1;
    *(uint*)(tl + row * 256 + ((lane * 4) ^ ((row & 7) << 4))) = *(uint*)&s;
  }
  __syncthreads();

  const int row = lane & 31;
  const int khb = (lane >> 5) * 16;
  const int swz = (row & 7) << 4;
  f32x16 z = {};
#pragma unroll
  for (int ks = 0; ks < 8; ks++) {
    bf16x8 a = *(const bf16x8*)(tl + row * 256 + ((ks * 32 + khb) ^ swz));
    z = __builtin_amdgcn_mfma_f32_32x32x16_bf16(a, a, z, 0, 0, 0);
  }

  ushort* Rb = R + (size_t)b * 512;
  *(uint*)(Rb + lane * 2) = *(const uint*)(tl + lane * 4);
  if (lane < 33) Rb[479 + lane] = 0;
  const int j = lane & 31;
  const int rb4 = (lane >> 5) * 4;
#pragma unroll
  for (int r = 0; r < 16; r++) {
    int i = (r & 3) + 8 * (r >> 2) + rb4;
    if (i <= 26 && j < i) Rb[DIM + (i * (i - 1)) / 2 + j] = f2b(z[r]);
  }
}

// ---------------- deep-pipelined bf16 GEMM: BM=256 BN=128 BK=64, 3-slot ring ----------------
// 512 threads = 8 waves (2M x 4N), per-wave 128x32 output (8x2 16x16 frags).
// K-step kt: compute from slot[kt%3]; stage kt+2 into slot[(kt+2)%3] (freed at kt's barrier).
// Counted vmcnt(6) per K-step (6 loads/K-step in flight for kt+1), raw s_barrier (no drain).
// LDS tiles XOR-swizzled: lds[row][cb] = global[row][cb ^ ((row&7)<<4)] via pre-swizzled src.
#define SLOT_BYTES 49152   // A: 256x64 bf16 = 32KB, B: 128x64 bf16 = 16KB
template <int ACT>
__global__ __launch_bounds__(512, 2) void gemm256_kernel(
    const ushort* __restrict__ A, const ushort* __restrict__ W,
    const float* __restrict__ bias, ushort* __restrict__ C, int K, int ldc) {
  __shared__ char lds[3 * SLOT_BYTES];
  const int tid = threadIdx.x;
  const int lane = tid & 63, wid = tid >> 6;
  const int wm = wid >> 2, wn = wid & 3;
  const int m0 = blockIdx.y * 256, n0 = blockIdx.x * 128;
  const int NK = K >> 6;

  const int srow = tid >> 3;           // staging row within 64-row group
  const int scolb = (tid & 7) << 4;    // staging col byte 0..112

  // prologue: stage K-steps 0 and 1
#pragma unroll
  for (int kt = 0; kt < 2; kt++) {
    char* As = lds + kt * SLOT_BYTES;
    char* Bs = As + 32768;
    const int k0 = kt * 64;
#pragma unroll
    for (int i = 0; i < 4; i++) {
      int row = i * 64 + srow;
      int colb = scolb ^ ((row & 7) << 4);
      gload_lds16(A + (size_t)(m0 + row) * K + k0 + (colb >> 1), As + i * 8192 + wid * 1024);
    }
#pragma unroll
    for (int i = 0; i < 2; i++) {
      int row = i * 64 + srow;
      int colb = scolb ^ ((row & 7) << 4);
      gload_lds16(W + (size_t)(n0 + row) * K + k0 + (colb >> 1), Bs + i * 8192 + wid * 1024);
    }
  }

  f32x4 acc[8][2] = {};
  const int fr = lane & 15;
  const int fkb = (lane >> 4) * 16;    // byte offset of lane's 8 bf16 within k-half

  for (int kt = 0; kt < NK; kt++) {
    if (kt + 1 < NK) { asm volatile("s_waitcnt vmcnt(6)" ::: "memory"); }
    else             { asm volatile("s_waitcnt vmcnt(0)" ::: "memory"); }
    __builtin_amdgcn_sched_barrier(0);
    __builtin_amdgcn_s_barrier();
    __builtin_amdgcn_sched_barrier(0);

    const char* As = lds + (kt % 3) * SLOT_BYTES;
    const char* Bs = As + 32768;

    bf16x8 a[2][8], b[2][2];
#pragma unroll
    for (int kh = 0; kh < 2; kh++) {
#pragma unroll
      for (int mf = 0; mf < 8; mf++) {
        int row = wm * 128 + mf * 16 + fr;
        int colb = (kh * 64 + fkb) ^ ((row & 7) << 4);
        a[kh][mf] = *(const bf16x8*)(As + row * 128 + colb);
      }
#pragma unroll
      for (int nf = 0; nf < 2; nf++) {
        int row = wn * 32 + nf * 16 + fr;
        int colb = (kh * 64 + fkb) ^ ((row & 7) << 4);
        b[kh][nf] = *(const bf16x8*)(Bs + row * 128 + colb);
      }
    }

    if (kt + 2 < NK) {   // stage kt+2 into its (consumed) slot
      char* Ad = lds + ((kt + 2) % 3) * SLOT_BYTES;
      char* Bd = Ad + 32768;
      const int k0 = (kt + 2) * 64;
#pragma unroll
      for (int i = 0; i < 4; i++) {
        int row = i * 64 + srow;
        int colb = scolb ^ ((row & 7) << 4);
        gload_lds16(A + (size_t)(m0 + row) * K + k0 + (colb >> 1), Ad + i * 8192 + wid * 1024);
      }
#pragma unroll
      for (int i = 0; i < 2; i++) {
        int row = i * 64 + srow;
        int colb = scolb ^ ((row & 7) << 4);
        gload_lds16(W + (size_t)(n0 + row) * K + k0 + (colb >> 1), Bd + i * 8192 + wid * 1024);
      }
    }

    __builtin_amdgcn_s_setprio(1);
#pragma unroll
    for (int kh = 0; kh < 2; kh++)
#pragma unroll
      for (int mf = 0; mf < 8; mf++)
#pragma unroll
        for (int nf = 0; nf < 2; nf++)
          acc[mf][nf] = __builtin_amdgcn_mfma_f32_16x16x32_bf16(a[kh][mf], b[kh][nf], acc[mf][nf], 0, 0, 0);
    __builtin_amdgcn_s_setprio(0);
  }

  const int cr = lane & 15, rh = (lane >> 4) * 4;
#pragma unroll
  for (int nf = 0; nf < 2; nf++) {
    int n = n0 + wn * 32 + nf * 16 + cr;
    float bs = bias[n];
#pragma unroll
    for (int mf = 0; mf < 8; mf++) {
      int mb = m0 + wm * 128 + mf * 16 + rh;
#pragma unroll
      for (int r = 0; r < 4; r++) {
        float v = acc[mf][nf][r] + bs;
        if (ACT) v = fmaxf(v, 0.f);
        C[(size_t)(mb + r) * ldc + n] = f2b(v);
      }
    }
  }
}

// ---------------- 128x128 m97-structure GEMM (small layers) ----------------
template <int ACT>
__global__ __launch_bounds__(256) void gemm_bf16_kernel(
    const ushort* __restrict__ A, const ushort* __restrict__ W,
    const float* __restrict__ bias, ushort* __restrict__ C, int K, int ldc) {
  __shared__ ushort As[128 * 32];
  __shared__ ushort Bs[128 * 32];
  const int tid = threadIdx.x;
  const int lane = tid & 63, wave = tid >> 6;
  const int m0 = blockIdx.y * 128, n0 = blockIdx.x * 128;
  const int wr = wave >> 1, wc = wave & 1;

  const int srow = lane >> 2;
  const int skp = (lane & 3) * 8;
  const ushort* Ag = A + (size_t)(m0 + wave * 16 + srow) * K + skp;
  const ushort* Wg = W + (size_t)(n0 + wave * 16 + srow) * K + skp;
  ushort* AsW = &As[(wave * 16) * 32];
  ushort* BsW = &Bs[(wave * 16) * 32];

  f32x4 acc[4][4] = {};
  const int fr = lane & 15;
  const int fk = (lane >> 4) * 8;

  for (int k0 = 0; k0 < K; k0 += 32) {
    gload_lds16(Ag + k0, AsW);
    gload_lds16(Ag + (size_t)64 * K + k0, AsW + 64 * 32);
    gload_lds16(Wg + k0, BsW);
    gload_lds16(Wg + (size_t)64 * K + k0, BsW + 64 * 32);
    __syncthreads();
    bf16x8 a[4], b[4];
#pragma unroll
    for (int i = 0; i < 4; i++) {
      a[i] = *(const bf16x8*)&As[(wr * 64 + i * 16 + fr) * 32 + fk];
      b[i] = *(const bf16x8*)&Bs[(wc * 64 + i * 16 + fr) * 32 + fk];
    }
#pragma unroll
    for (int i = 0; i < 4; i++)
#pragma unroll
      for (int j = 0; j < 4; j++)
        acc[i][j] = __builtin_amdgcn_mfma_f32_16x16x32_bf16(a[i], b[j], acc[i][j], 0, 0, 0);
    __syncthreads();
  }

  const int col_l = lane & 15, row_h = (lane >> 4) * 4;
#pragma unroll
  for (int j = 0; j < 4; j++) {
    int n = n0 + wc * 64 + j * 16 + col_l;
    float bs = bias[n];
#pragma unroll
    for (int i = 0; i < 4; i++) {
      int mbase = m0 + wr * 64 + i * 16 + row_h;
#pragma unroll
      for (int r = 0; r < 4; r++) {
        float v = acc[i][j][r] + bs;
        if (ACT) v = fmaxf(v, 0.f);
        C[(size_t)(mbase + r) * ldc + n] = f2b(v);
      }
    }
  }
}

// ---------------- final layer: out[b] = sigmoid(dot(A[b], w) + bias), K=256 bf16 in ----------------
__global__ __launch_bounds__(256) void final_kernel(const ushort* __restrict__ A,
    const float* __restrict__ w, const float* __restrict__ bias, float* __restrict__ out) {
  int row = blockIdx.x * 4 + (threadIdx.x >> 6);
  int lane = threadIdx.x & 63;
  ushort4 a4 = ((const ushort4*)(A + (size_t)row * 256))[lane];
  float4 wv = ((const float4*)w)[lane];
  float s = b2f(a4.x) * wv.x + b2f(a4.y) * wv.y + b2f(a4.z) * wv.z + b2f(a4.w) * wv.w;
#pragma unroll
  for (int off = 32; off >= 1; off >>= 1) s += __shfl_xor(s, off);
  if (lane == 0) out[row] = 1.f / (1.f + expf(-(s + bias[0])));
}

extern "C" void kernel_launch(void* const* d_in, const int* in_sizes, int n_in,
                              void* d_out, int out_size, void* d_ws, size_t ws_size,
                              hipStream_t stream) {
  const float* dense_x = (const float*)d_in[0];
  const int* lS_i = (const int*)d_in[2];
  const float* emb = (const float*)d_in[3];
  const float* bw0 = (const float*)d_in[4];
  const float* bb0 = (const float*)d_in[5];
  const float* bw1 = (const float*)d_in[6];
  const float* bb1 = (const float*)d_in[7];
  const float* bw2 = (const float*)d_in[8];
  const float* bb2 = (const float*)d_in[9];
  const float* tw0 = (const float*)d_in[10];
  const float* tb0 = (const float*)d_in[11];
  const float* tw1 = (const float*)d_in[12];
  const float* tb1 = (const float*)d_in[13];
  const float* tw2 = (const float*)d_in[14];
  const float* tb2 = (const float*)d_in[15];
  const float* tw3 = (const float*)d_in[16];
  const float* tb3 = (const float*)d_in[17];
  float* out = (float*)d_out;

  // workspace layout (bf16)
  char* w = (char*)d_ws;
  ushort* xb  = (ushort*)w; w += (size_t)BATCH * 128 * 2;
  ushort* x1  = (ushort*)w; w += (size_t)BATCH * 512 * 2;
  ushort* x2  = (ushort*)w; w += (size_t)BATCH * 256 * 2;
  ushort* R   = (ushort*)w; w += (size_t)BATCH * 512 * 2;
  ushort* t1  = (ushort*)w; w += (size_t)BATCH * 1024 * 2;
  ushort* wb1 = (ushort*)w; w += 256 * 512 * 2;
  ushort* wb2 = (ushort*)w; w += 128 * 256 * 2;
  ushort* wt0 = (ushort*)w; w += 1024 * 512 * 2;
  ushort* wt1 = (ushort*)w; w += 512 * 1024 * 2;
  ushort* wt2 = (ushort*)w; w += 256 * 512 * 2;
  ushort* t2 = x1;   // reuse
  ushort* t3 = x2;   // reuse

  cvt_all_kernel<<<dim3(2048, 5), 256, 0, stream>>>(bw1, bw2, tw0, tw1, tw2,
                                                    wb1, wb2, wt0, wt1, wt2);

  // bottom MLP -> xb (packed B x 128)
  bot0_kernel<<<BATCH * 2, 256, 0, stream>>>(dense_x, bw0, bb0, x1);
  gemm_bf16_kernel<1><<<dim3(2, BATCH / 128), 256, 0, stream>>>(x1, wb1, bb1, x2, 512, 256);
  gemm_bf16_kernel<1><<<dim3(1, BATCH / 128), 256, 0, stream>>>(x2, wb2, bb2, xb, 256, 128);

  // fused embeddings + interaction -> R = [x | tril(Z) | 0pad]
  embint_kernel<<<BATCH / 4, 256, 0, stream>>>(emb, lS_i, xb, R);

  // top MLP: t0, t1 on deep-pipelined 256x128 kernel
  gemm256_kernel<1><<<dim3(1024 / 128, BATCH / 256), 512, 0, stream>>>(R,  wt0, tb0, t1, 512, 1024);
  gemm256_kernel<1><<<dim3(512 / 128,  BATCH / 256), 512, 0, stream>>>(t1, wt1, tb1, t2, 1024, 512);
  gemm_bf16_kernel<1><<<dim3(2, BATCH / 128), 256, 0, stream>>>(t2, wt2, tb2, t3, 512, 256);
  final_kernel<<<BATCH / 4, 256, 0, stream>>>(t3, tw3, tb3, out);
}

// Round 6
// 222.771 us; speedup vs baseline: 4.3140x; 1.0155x over previous
//
#include <hip/hip_runtime.h>
#include <hip/hip_bf16.h>
#include <math.h>

#define BATCH 16384
#define NTAB 26
#define DIM 128
#define NROWS 100000

typedef short bf16x8 __attribute__((ext_vector_type(8)));
typedef float f32x4 __attribute__((ext_vector_type(4)));
typedef float f32x16 __attribute__((ext_vector_type(16)));

__device__ __forceinline__ ushort f2b(float f) {   // fp32 -> bf16 RNE
  union { float f; unsigned u; } c; c.f = f;
  unsigned r = (c.u + 0x7fffu + ((c.u >> 16) & 1u)) >> 16;
  return (ushort)r;
}
__device__ __forceinline__ float b2f(ushort u) {
  union { unsigned u; float f; } c; c.u = (unsigned)u << 16;
  return c.f;
}

__device__ __forceinline__ void gload_lds16(const void* g, void* l) {
  __builtin_amdgcn_global_load_lds(
      (const __attribute__((address_space(1))) void*)g,
      (__attribute__((address_space(3))) void*)l, 16, 0, 0);
}

// ---------------- all weight fp32 -> bf16 conversions, one launch ----------------
__global__ __launch_bounds__(256) void cvt_all_kernel(
    const float* __restrict__ bw1, const float* __restrict__ bw2,
    const float* __restrict__ tw0, const float* __restrict__ tw1,
    const float* __restrict__ tw2,
    ushort* __restrict__ o1, ushort* __restrict__ o2, ushort* __restrict__ o3,
    ushort* __restrict__ o4, ushort* __restrict__ o5) {
  int i = blockIdx.x * 256 + threadIdx.x;
  switch (blockIdx.y) {
    case 0: if (i < 256 * 512) o1[i] = f2b(bw1[i]); break;
    case 1: if (i < 128 * 256) o2[i] = f2b(bw2[i]); break;
    case 2: if (i < 1024 * 512) {            // pad K 479 -> 512
      int r = i >> 9, c = i & 511;
      o3[i] = (c < 479) ? f2b(tw0[(size_t)r * 479 + c]) : (ushort)0;
    } break;
    case 3: if (i < 512 * 1024) o4[i] = f2b(tw1[i]); break;
    case 4: if (i < 256 * 512) o5[i] = f2b(tw2[i]); break;
  }
}

// ---------------- bottom layer 0: 13 -> 512, relu, bf16 out ----------------
__global__ __launch_bounds__(256) void bot0_kernel(const float* __restrict__ x,
    const float* __restrict__ W, const float* __restrict__ bias, ushort* __restrict__ y) {
  int b = blockIdx.x >> 1;
  int m = ((blockIdx.x & 1) << 8) | threadIdx.x;
  const float* xr = x + (size_t)b * 13;
  const float* wr = W + (size_t)m * 13;
  float acc = bias[m];
#pragma unroll
  for (int k = 0; k < 13; k++) acc = fmaf(xr[k], wr[k], acc);
  y[(size_t)b * 512 + m] = f2b(fmaxf(acc, 0.f));
}

// ---------------- fused embedding gather+pool+interaction ----------------
__global__ __launch_bounds__(256) void embint_kernel(
    const float* __restrict__ tables, const int* __restrict__ lS_i,
    const ushort* __restrict__ xb, ushort* __restrict__ R) {
  __shared__ ushort Tls[4][32 * 128];          // 8 KB per wave
  const int wave = threadIdx.x >> 6, lane = threadIdx.x & 63;
  const int b = blockIdx.x * 4 + wave;
  char* tl = (char*)Tls[wave];

  *(uint*)(tl + lane * 4) = *(const uint*)(xb + (size_t)b * 128 + lane * 2);
#pragma unroll
  for (int r = 27; r < 32; r++)
    *(uint*)(tl + r * 256 + ((lane * 4) ^ ((r & 7) << 4))) = 0;
#pragma unroll 4
  for (int t = 0; t < NTAB; t++) {
    const int* idx = lS_i + ((size_t)t << 15) + (b << 1);
    int i0 = idx[0], i1 = idx[1];
    float2 v0 = ((const float2*)(tables + ((size_t)t * NROWS + i0) * DIM))[lane];
    float2 v1 = ((const float2*)(tables + ((size_t)t * NROWS + i1) * DIM))[lane];
    ushort2 s; s.x = f2b(v0.x + v1.x); s.y = f2b(v0.y + v1.y);
    int row = t + 1;
    *(uint*)(tl + row * 256 + ((lane * 4) ^ ((row & 7) << 4))) = *(uint*)&s;
  }
  __syncthreads();

  const int row = lane & 31;
  const int khb = (lane >> 5) * 16;
  const int swz = (row & 7) << 4;
  f32x16 z = {};
#pragma unroll
  for (int ks = 0; ks < 8; ks++) {
    bf16x8 a = *(const bf16x8*)(tl + row * 256 + ((ks * 32 + khb) ^ swz));
    z = __builtin_amdgcn_mfma_f32_32x32x16_bf16(a, a, z, 0, 0, 0);
  }

  ushort* Rb = R + (size_t)b * 512;
  *(uint*)(Rb + lane * 2) = *(const uint*)(tl + lane * 4);
  if (lane < 33) Rb[479 + lane] = 0;
  const int j = lane & 31;
  const int rb4 = (lane >> 5) * 4;
#pragma unroll
  for (int r = 0; r < 16; r++) {
    int i = (r & 3) + 8 * (r >> 2) + rb4;
    if (i <= 26 && j < i) Rb[DIM + (i * (i - 1)) / 2 + j] = f2b(z[r]);
  }
}

// ---------------- deep-pipelined bf16 GEMM: BM=256 BN=128 BK=64, 3-slot ring ----------------
// 512 threads = 8 waves (2M x 4N), per-wave 128x32 output (8x2 16x16 frags).
// 2-phase K-step (m201 skeleton): per k-half {10 ds_read | 3 stage-issues ->
// s_barrier -> lgkmcnt(0) -> setprio(1) -> 16 MFMA -> setprio(0) -> s_barrier}.
// Counted vmcnt(6) once per K-step; 3-slot ring (compute kt, stage kt+2).
// XCD-chunked bijective block swizzle clusters same-A-panel blocks per XCD L2.
#define SLOT_BYTES 49152   // A: 256x64 bf16 = 32KB, B: 128x64 bf16 = 16KB
template <int ACT>
__global__ __launch_bounds__(512, 2) void gemm256_kernel(
    const ushort* __restrict__ A, const ushort* __restrict__ W,
    const float* __restrict__ bias, ushort* __restrict__ C, int K, int ldc) {
  __shared__ char lds[3 * SLOT_BYTES];
  const int tid = threadIdx.x;
  const int lane = tid & 63, wid = tid >> 6;
  const int wm = wid >> 2, wn = wid & 3;

  // bijective XCD-chunked swizzle (m204): consecutive tiles of a panel -> same XCD
  const int nwg = gridDim.x * gridDim.y;
  const int orig = blockIdx.y * gridDim.x + blockIdx.x;
  const int q = nwg >> 3, r8 = nwg & 7;
  const int xcd = orig & 7, pos = orig >> 3;
  const int swzid = (xcd < r8 ? xcd * (q + 1) : r8 * (q + 1) + (xcd - r8) * q) + pos;
  const int m0 = (swzid / gridDim.x) * 256, n0 = (swzid % gridDim.x) * 128;
  const int NK = K >> 6;

  const int srow = tid >> 3;           // staging row within 64-row group
  const int scolb = (tid & 7) << 4;    // staging col byte 0..112

  // prologue: stage K-steps 0 and 1
#pragma unroll
  for (int kt = 0; kt < 2; kt++) {
    char* As = lds + kt * SLOT_BYTES;
    char* Bs = As + 32768;
    const int k0 = kt * 64;
#pragma unroll
    for (int i = 0; i < 4; i++) {
      int row = i * 64 + srow;
      int colb = scolb ^ ((row & 7) << 4);
      gload_lds16(A + (size_t)(m0 + row) * K + k0 + (colb >> 1), As + i * 8192 + wid * 1024);
    }
#pragma unroll
    for (int i = 0; i < 2; i++) {
      int row = i * 64 + srow;
      int colb = scolb ^ ((row & 7) << 4);
      gload_lds16(W + (size_t)(n0 + row) * K + k0 + (colb >> 1), Bs + i * 8192 + wid * 1024);
    }
  }

  f32x4 acc[8][2] = {};
  const int fr = lane & 15;
  const int fkb = (lane >> 4) * 16;    // byte offset of lane's 8 bf16 within k-half

  for (int kt = 0; kt < NK; kt++) {
    if (kt + 1 < NK) { asm volatile("s_waitcnt vmcnt(6)" ::: "memory"); }
    else             { asm volatile("s_waitcnt vmcnt(0)" ::: "memory"); }
    __builtin_amdgcn_sched_barrier(0);
    __builtin_amdgcn_s_barrier();
    __builtin_amdgcn_sched_barrier(0);

    const char* As = lds + (kt % 3) * SLOT_BYTES;
    const char* Bs = As + 32768;
    char* Ad = lds + ((kt + 2) % 3) * SLOT_BYTES;
    char* Bd = Ad + 32768;
    const int k2 = (kt + 2) * 64;
    const bool do_stage = (kt + 2 < NK);

#pragma unroll
    for (int kh = 0; kh < 2; kh++) {
      bf16x8 a[8], b[2];
#pragma unroll
      for (int mf = 0; mf < 8; mf++) {
        int row = wm * 128 + mf * 16 + fr;
        int colb = (kh * 64 + fkb) ^ ((row & 7) << 4);
        a[mf] = *(const bf16x8*)(As + row * 128 + colb);
      }
#pragma unroll
      for (int nf = 0; nf < 2; nf++) {
        int row = wn * 32 + nf * 16 + fr;
        int colb = (kh * 64 + fkb) ^ ((row & 7) << 4);
        b[nf] = *(const bf16x8*)(Bs + row * 128 + colb);
      }
      if (do_stage) {
        // split the 6 stage loads: 3 in phase 0 (A halves 0,1 + B half 0),
        // 3 in phase 1 (A halves 2,3 + B half 1)
#pragma unroll
        for (int i = kh * 2; i < kh * 2 + 2; i++) {
          int row = i * 64 + srow;
          int colb = scolb ^ ((row & 7) << 4);
          gload_lds16(A + (size_t)(m0 + row) * K + k2 + (colb >> 1), Ad + i * 8192 + wid * 1024);
        }
        {
          int row = kh * 64 + srow;
          int colb = scolb ^ ((row & 7) << 4);
          gload_lds16(W + (size_t)(n0 + row) * K + k2 + (colb >> 1), Bd + kh * 8192 + wid * 1024);
        }
      }
      __builtin_amdgcn_sched_barrier(0);
      __builtin_amdgcn_s_barrier();
      asm volatile("s_waitcnt lgkmcnt(0)" ::: "memory");
      __builtin_amdgcn_sched_barrier(0);
      __builtin_amdgcn_s_setprio(1);
#pragma unroll
      for (int mf = 0; mf < 8; mf++)
#pragma unroll
        for (int nf = 0; nf < 2; nf++)
          acc[mf][nf] = __builtin_amdgcn_mfma_f32_16x16x32_bf16(a[mf], b[nf], acc[mf][nf], 0, 0, 0);
      __builtin_amdgcn_s_setprio(0);
      if (kh == 0) {
        __builtin_amdgcn_sched_barrier(0);
        __builtin_amdgcn_s_barrier();
        __builtin_amdgcn_sched_barrier(0);
      }
    }
  }

  const int cr = lane & 15, rh = (lane >> 4) * 4;
#pragma unroll
  for (int nf = 0; nf < 2; nf++) {
    int n = n0 + wn * 32 + nf * 16 + cr;
    float bs = bias[n];
#pragma unroll
    for (int mf = 0; mf < 8; mf++) {
      int mb = m0 + wm * 128 + mf * 16 + rh;
#pragma unroll
      for (int r = 0; r < 4; r++) {
        float v = acc[mf][nf][r] + bs;
        if (ACT) v = fmaxf(v, 0.f);
        C[(size_t)(mb + r) * ldc + n] = f2b(v);
      }
    }
  }
}

// ---------------- 128x128 m97-structure GEMM (small layers) ----------------
template <int ACT>
__global__ __launch_bounds__(256) void gemm_bf16_kernel(
    const ushort* __restrict__ A, const ushort* __restrict__ W,
    const float* __restrict__ bias, ushort* __restrict__ C, int K, int ldc) {
  __shared__ ushort As[128 * 32];
  __shared__ ushort Bs[128 * 32];
  const int tid = threadIdx.x;
  const int lane = tid & 63, wave = tid >> 6;
  const int m0 = blockIdx.y * 128, n0 = blockIdx.x * 128;
  const int wr = wave >> 1, wc = wave & 1;

  const int srow = lane >> 2;
  const int skp = (lane & 3) * 8;
  const ushort* Ag = A + (size_t)(m0 + wave * 16 + srow) * K + skp;
  const ushort* Wg = W + (size_t)(n0 + wave * 16 + srow) * K + skp;
  ushort* AsW = &As[(wave * 16) * 32];
  ushort* BsW = &Bs[(wave * 16) * 32];

  f32x4 acc[4][4] = {};
  const int fr = lane & 15;
  const int fk = (lane >> 4) * 8;

  for (int k0 = 0; k0 < K; k0 += 32) {
    gload_lds16(Ag + k0, AsW);
    gload_lds16(Ag + (size_t)64 * K + k0, AsW + 64 * 32);
    gload_lds16(Wg + k0, BsW);
    gload_lds16(Wg + (size_t)64 * K + k0, BsW + 64 * 32);
    __syncthreads();
    bf16x8 a[4], b[4];
#pragma unroll
    for (int i = 0; i < 4; i++) {
      a[i] = *(const bf16x8*)&As[(wr * 64 + i * 16 + fr) * 32 + fk];
      b[i] = *(const bf16x8*)&Bs[(wc * 64 + i * 16 + fr) * 32 + fk];
    }
#pragma unroll
    for (int i = 0; i < 4; i++)
#pragma unroll
      for (int j = 0; j < 4; j++)
        acc[i][j] = __builtin_amdgcn_mfma_f32_16x16x32_bf16(a[i], b[j], acc[i][j], 0, 0, 0);
    __syncthreads();
  }

  const int col_l = lane & 15, row_h = (lane >> 4) * 4;
#pragma unroll
  for (int j = 0; j < 4; j++) {
    int n = n0 + wc * 64 + j * 16 + col_l;
    float bs = bias[n];
#pragma unroll
    for (int i = 0; i < 4; i++) {
      int mbase = m0 + wr * 64 + i * 16 + row_h;
#pragma unroll
      for (int r = 0; r < 4; r++) {
        float v = acc[i][j][r] + bs;
        if (ACT) v = fmaxf(v, 0.f);
        C[(size_t)(mbase + r) * ldc + n] = f2b(v);
      }
    }
  }
}

// ---------------- final layer: out[b] = sigmoid(dot(A[b], w) + bias), K=256 bf16 in ----------------
__global__ __launch_bounds__(256) void final_kernel(const ushort* __restrict__ A,
    const float* __restrict__ w, const float* __restrict__ bias, float* __restrict__ out) {
  int row = blockIdx.x * 4 + (threadIdx.x >> 6);
  int lane = threadIdx.x & 63;
  ushort4 a4 = ((const ushort4*)(A + (size_t)row * 256))[lane];
  float4 wv = ((const float4*)w)[lane];
  float s = b2f(a4.x) * wv.x + b2f(a4.y) * wv.y + b2f(a4.z) * wv.z + b2f(a4.w) * wv.w;
#pragma unroll
  for (int off = 32; off >= 1; off >>= 1) s += __shfl_xor(s, off);
  if (lane == 0) out[row] = 1.f / (1.f + expf(-(s + bias[0])));
}

extern "C" void kernel_launch(void* const* d_in, const int* in_sizes, int n_in,
                              void* d_out, int out_size, void* d_ws, size_t ws_size,
                              hipStream_t stream) {
  const float* dense_x = (const float*)d_in[0];
  const int* lS_i = (const int*)d_in[2];
  const float* emb = (const float*)d_in[3];
  const float* bw0 = (const float*)d_in[4];
  const float* bb0 = (const float*)d_in[5];
  const float* bw1 = (const float*)d_in[6];
  const float* bb1 = (const float*)d_in[7];
  const float* bw2 = (const float*)d_in[8];
  const float* bb2 = (const float*)d_in[9];
  const float* tw0 = (const float*)d_in[10];
  const float* tb0 = (const float*)d_in[11];
  const float* tw1 = (const float*)d_in[12];
  const float* tb1 = (const float*)d_in[13];
  const float* tw2 = (const float*)d_in[14];
  const float* tb2 = (const float*)d_in[15];
  const float* tw3 = (const float*)d_in[16];
  const float* tb3 = (const float*)d_in[17];
  float* out = (float*)d_out;

  // workspace layout (bf16)
  char* w = (char*)d_ws;
  ushort* xb  = (ushort*)w; w += (size_t)BATCH * 128 * 2;
  ushort* x1  = (ushort*)w; w += (size_t)BATCH * 512 * 2;
  ushort* x2  = (ushort*)w; w += (size_t)BATCH * 256 * 2;
  ushort* R   = (ushort*)w; w += (size_t)BATCH * 512 * 2;
  ushort* t1  = (ushort*)w; w += (size_t)BATCH * 1024 * 2;
  ushort* wb1 = (ushort*)w; w += 256 * 512 * 2;
  ushort* wb2 = (ushort*)w; w += 128 * 256 * 2;
  ushort* wt0 = (ushort*)w; w += 1024 * 512 * 2;
  ushort* wt1 = (ushort*)w; w += 512 * 1024 * 2;
  ushort* wt2 = (ushort*)w; w += 256 * 512 * 2;
  ushort* t2 = x1;   // reuse
  ushort* t3 = x2;   // reuse

  cvt_all_kernel<<<dim3(2048, 5), 256, 0, stream>>>(bw1, bw2, tw0, tw1, tw2,
                                                    wb1, wb2, wt0, wt1, wt2);

  // bottom MLP -> xb (packed B x 128)
  bot0_kernel<<<BATCH * 2, 256, 0, stream>>>(dense_x, bw0, bb0, x1);
  gemm_bf16_kernel<1><<<dim3(2, BATCH / 128), 256, 0, stream>>>(x1, wb1, bb1, x2, 512, 256);
  gemm_bf16_kernel<1><<<dim3(1, BATCH / 128), 256, 0, stream>>>(x2, wb2, bb2, xb, 256, 128);

  // fused embeddings + interaction -> R = [x | tril(Z) | 0pad]
  embint_kernel<<<BATCH / 4, 256, 0, stream>>>(emb, lS_i, xb, R);

  // top MLP: t0, t1 on deep-pipelined 256x128 kernel
  gemm256_kernel<1><<<dim3(1024 / 128, BATCH / 256), 512, 0, stream>>>(R,  wt0, tb0, t1, 512, 1024);
  gemm256_kernel<1><<<dim3(512 / 128,  BATCH / 256), 512, 0, stream>>>(t1, wt1, tb1, t2, 1024, 512);
  gemm_bf16_kernel<1><<<dim3(2, BATCH / 128), 256, 0, stream>>>(t2, wt2, tb2, t3, 512, 256);
  final_kernel<<<BATCH / 4, 256, 0, stream>>>(t3, tw3, tb3, out);
}

// Round 7
// 218.029 us; speedup vs baseline: 4.4078x; 1.0217x over previous
//
#include <hip/hip_runtime.h>
#include <hip/hip_bf16.h>
#include <math.h>

#define BATCH 16384
#define NTAB 26
#define DIM 128
#define NROWS 100000

typedef short bf16x8 __attribute__((ext_vector_type(8)));
typedef float f32x4 __attribute__((ext_vector_type(4)));
typedef float f32x16 __attribute__((ext_vector_type(16)));

__device__ __forceinline__ ushort f2b(float f) {   // fp32 -> bf16 RNE
  union { float f; unsigned u; } c; c.f = f;
  unsigned r = (c.u + 0x7fffu + ((c.u >> 16) & 1u)) >> 16;
  return (ushort)r;
}
__device__ __forceinline__ float b2f(ushort u) {
  union { unsigned u; float f; } c; c.u = (unsigned)u << 16;
  return c.f;
}

__device__ __forceinline__ void gload_lds16(const void* g, void* l) {
  __builtin_amdgcn_global_load_lds(
      (const __attribute__((address_space(1))) void*)g,
      (__attribute__((address_space(3))) void*)l, 16, 0, 0);
}

// ---------------- prep: bottom layer 0 (13->512 relu) + all weight cvt, one launch ----------------
__global__ __launch_bounds__(256) void prep_kernel(
    const float* __restrict__ x, const float* __restrict__ W0,
    const float* __restrict__ b0, ushort* __restrict__ y,
    const float* __restrict__ bw1, const float* __restrict__ bw2,
    const float* __restrict__ tw0, const float* __restrict__ tw1,
    const float* __restrict__ tw2,
    ushort* __restrict__ o1, ushort* __restrict__ o2, ushort* __restrict__ o3,
    ushort* __restrict__ o4, ushort* __restrict__ o5) {
  int blk = blockIdx.x;
  if (blk < 2 * BATCH) {
    int b = blk >> 1;
    int m = ((blk & 1) << 8) | threadIdx.x;
    const float* xr = x + (size_t)b * 13;
    const float* wr = W0 + (size_t)m * 13;
    float acc = b0[m];
#pragma unroll
    for (int k = 0; k < 13; k++) acc = fmaf(xr[k], wr[k], acc);
    y[(size_t)b * 512 + m] = f2b(fmaxf(acc, 0.f));
    return;
  }
  int cb = blk - 2 * BATCH;
  int c = cb >> 11;
  int i = (cb & 2047) * 256 + threadIdx.x;
  switch (c) {
    case 0: if (i < 256 * 512) o1[i] = f2b(bw1[i]); break;
    case 1: if (i < 128 * 256) o2[i] = f2b(bw2[i]); break;
    case 2: if (i < 1024 * 512) {            // pad K 479 -> 512
      int r = i >> 9, cc = i & 511;
      o3[i] = (cc < 479) ? f2b(tw0[(size_t)r * 479 + cc]) : (ushort)0;
    } break;
    case 3: if (i < 512 * 1024) o4[i] = f2b(tw1[i]); break;
    case 4: if (i < 256 * 512) o5[i] = f2b(tw2[i]); break;
  }
}

// ---------------- fused embedding gather+pool+interaction ----------------
__global__ __launch_bounds__(256) void embint_kernel(
    const float* __restrict__ tables, const int* __restrict__ lS_i,
    const ushort* __restrict__ xb, ushort* __restrict__ R) {
  __shared__ ushort Tls[4][32 * 128];          // 8 KB per wave
  const int wave = threadIdx.x >> 6, lane = threadIdx.x & 63;
  const int b = blockIdx.x * 4 + wave;
  char* tl = (char*)Tls[wave];

  *(uint*)(tl + lane * 4) = *(const uint*)(xb + (size_t)b * 128 + lane * 2);
#pragma unroll
  for (int r = 27; r < 32; r++)
    *(uint*)(tl + r * 256 + ((lane * 4) ^ ((r & 7) << 4))) = 0;
#pragma unroll 8
  for (int t = 0; t < NTAB; t++) {
    const int* idx = lS_i + ((size_t)t << 15) + (b << 1);
    int i0 = idx[0], i1 = idx[1];
    float2 v0 = ((const float2*)(tables + ((size_t)t * NROWS + i0) * DIM))[lane];
    float2 v1 = ((const float2*)(tables + ((size_t)t * NROWS + i1) * DIM))[lane];
    ushort2 s; s.x = f2b(v0.x + v1.x); s.y = f2b(v0.y + v1.y);
    int row = t + 1;
    *(uint*)(tl + row * 256 + ((lane * 4) ^ ((row & 7) << 4))) = *(uint*)&s;
  }
  __syncthreads();

  const int row = lane & 31;
  const int khb = (lane >> 5) * 16;
  const int swz = (row & 7) << 4;
  f32x16 z = {};
#pragma unroll
  for (int ks = 0; ks < 8; ks++) {
    bf16x8 a = *(const bf16x8*)(tl + row * 256 + ((ks * 32 + khb) ^ swz));
    z = __builtin_amdgcn_mfma_f32_32x32x16_bf16(a, a, z, 0, 0, 0);
  }

  ushort* Rb = R + (size_t)b * 512;
  *(uint*)(Rb + lane * 2) = *(const uint*)(tl + lane * 4);
  if (lane < 33) Rb[479 + lane] = 0;
  const int j = lane & 31;
  const int rb4 = (lane >> 5) * 4;
#pragma unroll
  for (int r = 0; r < 16; r++) {
    int i = (r & 3) + 8 * (r >> 2) + rb4;
    if (i <= 26 && j < i) Rb[DIM + (i * (i - 1)) / 2 + j] = f2b(z[r]);
  }
}

// ---------------- deep-pipelined bf16 GEMM: BM=256 BN=128 BK=64, 3-slot ring ----------------
#define SLOT_BYTES 49152   // A: 256x64 bf16 = 32KB, B: 128x64 bf16 = 16KB
template <int ACT>
__global__ __launch_bounds__(512, 2) void gemm256_kernel(
    const ushort* __restrict__ A, const ushort* __restrict__ W,
    const float* __restrict__ bias, ushort* __restrict__ C, int K, int ldc) {
  __shared__ char lds[3 * SLOT_BYTES];
  const int tid = threadIdx.x;
  const int lane = tid & 63, wid = tid >> 6;
  const int wm = wid >> 2, wn = wid & 3;

  // bijective XCD-chunked swizzle (m204)
  const int nwg = gridDim.x * gridDim.y;
  const int orig = blockIdx.y * gridDim.x + blockIdx.x;
  const int q = nwg >> 3, r8 = nwg & 7;
  const int xcd = orig & 7, pos = orig >> 3;
  const int swzid = (xcd < r8 ? xcd * (q + 1) : r8 * (q + 1) + (xcd - r8) * q) + pos;
  const int m0 = (swzid / gridDim.x) * 256, n0 = (swzid % gridDim.x) * 128;
  const int NK = K >> 6;

  const int srow = tid >> 3;           // staging row within 64-row group
  const int scolb = (tid & 7) << 4;    // staging col byte 0..112

  // prologue: stage K-steps 0 and 1
#pragma unroll
  for (int kt = 0; kt < 2; kt++) {
    char* As = lds + kt * SLOT_BYTES;
    char* Bs = As + 32768;
    const int k0 = kt * 64;
#pragma unroll
    for (int i = 0; i < 4; i++) {
      int row = i * 64 + srow;
      int colb = scolb ^ ((row & 7) << 4);
      gload_lds16(A + (size_t)(m0 + row) * K + k0 + (colb >> 1), As + i * 8192 + wid * 1024);
    }
#pragma unroll
    for (int i = 0; i < 2; i++) {
      int row = i * 64 + srow;
      int colb = scolb ^ ((row & 7) << 4);
      gload_lds16(W + (size_t)(n0 + row) * K + k0 + (colb >> 1), Bs + i * 8192 + wid * 1024);
    }
  }

  f32x4 acc[8][2] = {};
  const int fr = lane & 15;
  const int fkb = (lane >> 4) * 16;

  for (int kt = 0; kt < NK; kt++) {
    if (kt + 1 < NK) { asm volatile("s_waitcnt vmcnt(6)" ::: "memory"); }
    else             { asm volatile("s_waitcnt vmcnt(0)" ::: "memory"); }
    __builtin_amdgcn_sched_barrier(0);
    __builtin_amdgcn_s_barrier();
    __builtin_amdgcn_sched_barrier(0);

    const char* As = lds + (kt % 3) * SLOT_BYTES;
    const char* Bs = As + 32768;
    char* Ad = lds + ((kt + 2) % 3) * SLOT_BYTES;
    char* Bd = Ad + 32768;
    const int k2 = (kt + 2) * 64;
    const bool do_stage = (kt + 2 < NK);

#pragma unroll
    for (int kh = 0; kh < 2; kh++) {
      bf16x8 a[8], b[2];
#pragma unroll
      for (int mf = 0; mf < 8; mf++) {
        int row = wm * 128 + mf * 16 + fr;
        int colb = (kh * 64 + fkb) ^ ((row & 7) << 4);
        a[mf] = *(const bf16x8*)(As + row * 128 + colb);
      }
#pragma unroll
      for (int nf = 0; nf < 2; nf++) {
        int row = wn * 32 + nf * 16 + fr;
        int colb = (kh * 64 + fkb) ^ ((row & 7) << 4);
        b[nf] = *(const bf16x8*)(Bs + row * 128 + colb);
      }
      if (do_stage) {
#pragma unroll
        for (int i = kh * 2; i < kh * 2 + 2; i++) {
          int row = i * 64 + srow;
          int colb = scolb ^ ((row & 7) << 4);
          gload_lds16(A + (size_t)(m0 + row) * K + k2 + (colb >> 1), Ad + i * 8192 + wid * 1024);
        }
        {
          int row = kh * 64 + srow;
          int colb = scolb ^ ((row & 7) << 4);
          gload_lds16(W + (size_t)(n0 + row) * K + k2 + (colb >> 1), Bd + kh * 8192 + wid * 1024);
        }
      }
      __builtin_amdgcn_sched_barrier(0);
      __builtin_amdgcn_s_barrier();
      asm volatile("s_waitcnt lgkmcnt(0)" ::: "memory");
      __builtin_amdgcn_sched_barrier(0);
      __builtin_amdgcn_s_setprio(1);
#pragma unroll
      for (int mf = 0; mf < 8; mf++)
#pragma unroll
        for (int nf = 0; nf < 2; nf++)
          acc[mf][nf] = __builtin_amdgcn_mfma_f32_16x16x32_bf16(a[mf], b[nf], acc[mf][nf], 0, 0, 0);
      __builtin_amdgcn_s_setprio(0);
      if (kh == 0) {
        __builtin_amdgcn_sched_barrier(0);
        __builtin_amdgcn_s_barrier();
        __builtin_amdgcn_sched_barrier(0);
      }
    }
  }

  const int cr = lane & 15, rh = (lane >> 4) * 4;
#pragma unroll
  for (int nf = 0; nf < 2; nf++) {
    int n = n0 + wn * 32 + nf * 16 + cr;
    float bs = bias[n];
#pragma unroll
    for (int mf = 0; mf < 8; mf++) {
      int mb = m0 + wm * 128 + mf * 16 + rh;
#pragma unroll
      for (int r = 0; r < 4; r++) {
        float v = acc[mf][nf][r] + bs;
        if (ACT) v = fmaxf(v, 0.f);
        C[(size_t)(mb + r) * ldc + n] = f2b(v);
      }
    }
  }
}

// ---------------- 128x128 m97-structure GEMM (small layers), 4-way-swizzled LDS ----------------
template <int ACT>
__global__ __launch_bounds__(256) void gemm_bf16_kernel(
    const ushort* __restrict__ A, const ushort* __restrict__ W,
    const float* __restrict__ bias, ushort* __restrict__ C, int K, int ldc) {
  __shared__ ushort As[128 * 32];
  __shared__ ushort Bs[128 * 32];
  const int tid = threadIdx.x;
  const int lane = tid & 63, wave = tid >> 6;
  const int m0 = blockIdx.y * 128, n0 = blockIdx.x * 128;
  const int wr = wave >> 1, wc = wave & 1;

  const int srow = lane >> 2;
  const int scolb = ((lane & 3) << 4) ^ ((srow & 3) << 4);   // pre-swizzled src (row&3 swz, 64B rows)
  const ushort* Ag = A + (size_t)(m0 + wave * 16 + srow) * K + (scolb >> 1);
  const ushort* Wg = W + (size_t)(n0 + wave * 16 + srow) * K + (scolb >> 1);
  ushort* AsW = &As[(wave * 16) * 32];
  ushort* BsW = &Bs[(wave * 16) * 32];

  f32x4 acc[4][4] = {};
  const int fr = lane & 15;
  const int fkb = (lane >> 4) * 16;          // frag k byte offset
  const int fswz = (fr & 3) << 4;            // read-side swizzle

  for (int k0 = 0; k0 < K; k0 += 32) {
    gload_lds16(Ag + k0, AsW);
    gload_lds16(Ag + (size_t)64 * K + k0, AsW + 64 * 32);
    gload_lds16(Wg + k0, BsW);
    gload_lds16(Wg + (size_t)64 * K + k0, BsW + 64 * 32);
    __syncthreads();
    bf16x8 a[4], b[4];
#pragma unroll
    for (int i = 0; i < 4; i++) {
      a[i] = *(const bf16x8*)((const char*)As + (wr * 64 + i * 16 + fr) * 64 + (fkb ^ fswz));
      b[i] = *(const bf16x8*)((const char*)Bs + (wc * 64 + i * 16 + fr) * 64 + (fkb ^ fswz));
    }
#pragma unroll
    for (int i = 0; i < 4; i++)
#pragma unroll
      for (int j = 0; j < 4; j++)
        acc[i][j] = __builtin_amdgcn_mfma_f32_16x16x32_bf16(a[i], b[j], acc[i][j], 0, 0, 0);
    __syncthreads();
  }

  const int col_l = lane & 15, row_h = (lane >> 4) * 4;
#pragma unroll
  for (int j = 0; j < 4; j++) {
    int n = n0 + wc * 64 + j * 16 + col_l;
    float bs = bias[n];
#pragma unroll
    for (int i = 0; i < 4; i++) {
      int mbase = m0 + wr * 64 + i * 16 + row_h;
#pragma unroll
      for (int r = 0; r < 4; r++) {
        float v = acc[i][j][r] + bs;
        if (ACT) v = fmaxf(v, 0.f);
        C[(size_t)(mbase + r) * ldc + n] = f2b(v);
      }
    }
  }
}

// ---------------- fused t2 (512->256 relu) + final (256->1 sigmoid) ----------------
// 64 batch rows per block, 256 threads = 4 waves; wave w computes 64 rows x cols [w*64, w*64+64).
// GEMM tile kept in regs -> LDS -> per-row dot with tw3 -> sigmoid -> out.
__global__ __launch_bounds__(256) void t2final_kernel(
    const ushort* __restrict__ A, const ushort* __restrict__ W,
    const float* __restrict__ bias, const float* __restrict__ w3,
    const float* __restrict__ b3, float* __restrict__ out) {
  __shared__ char smem[64 * 264 * 2];        // 33.8 KB; As/Bs overlay in front
  ushort* As = (ushort*)smem;                // 64 x 32 (4 KB)
  ushort* Bs = (ushort*)(smem + 4096);       // 256 x 32 (16 KB)
  ushort* Ct = (ushort*)smem;                // 64 x 264 after compute
  const int tid = threadIdx.x;
  const int lane = tid & 63, wave = tid >> 6;
  const int m0 = blockIdx.x * 64;

  const int srow = lane >> 2;
  const int scolb = ((lane & 3) << 4) ^ ((srow & 3) << 4);
  const ushort* Ag = A + (size_t)(m0 + wave * 16 + srow) * 512 + (scolb >> 1);
  const ushort* Wg = W + (size_t)(wave * 16 + srow) * 512 + (scolb >> 1);

  f32x4 acc[4][4] = {};
  const int fr = lane & 15;
  const int fkb = (lane >> 4) * 16;
  const int fswz = (fr & 3) << 4;

  for (int k0 = 0; k0 < 512; k0 += 32) {
    gload_lds16(Ag + k0, (char*)As + wave * 1024);
#pragma unroll
    for (int i = 0; i < 4; i++)
      gload_lds16(Wg + (size_t)(i * 64) * 512 + k0, (char*)Bs + i * 4096 + wave * 1024);
    __syncthreads();
    bf16x8 a[4], b[4];
#pragma unroll
    for (int i = 0; i < 4; i++) {
      a[i] = *(const bf16x8*)((const char*)As + (i * 16 + fr) * 64 + (fkb ^ fswz));
      b[i] = *(const bf16x8*)((const char*)Bs + (wave * 64 + i * 16 + fr) * 64 + (fkb ^ fswz));
    }
#pragma unroll
    for (int i = 0; i < 4; i++)
#pragma unroll
      for (int j = 0; j < 4; j++)
        acc[i][j] = __builtin_amdgcn_mfma_f32_16x16x32_bf16(a[i], b[j], acc[i][j], 0, 0, 0);
    __syncthreads();
  }

  // acc -> Ct (bias+relu, bf16). C/D layout: col=lane&15, row=(lane>>4)*4+r.
  const int col_l = lane & 15, row_h = (lane >> 4) * 4;
#pragma unroll
  for (int j = 0; j < 4; j++) {
    int n = wave * 64 + j * 16 + col_l;
    float bs = bias[n];
#pragma unroll
    for (int i = 0; i < 4; i++) {
      int mb = i * 16 + row_h;
#pragma unroll
      for (int r = 0; r < 4; r++)
        Ct[(size_t)(mb + r) * 264 + n] = f2b(fmaxf(acc[i][j][r] + bs, 0.f));
    }
  }
  __syncthreads();

  // final: each wave handles 16 rows; lane covers 4 of 256 cols
  const float4 wv = ((const float4*)w3)[lane];
  const float bf = b3[0];
  for (int rr = 0; rr < 16; rr++) {
    int row = wave * 16 + rr;
    ushort4 a4 = *(const ushort4*)&Ct[(size_t)row * 264 + lane * 4];
    float s = b2f(a4.x) * wv.x + b2f(a4.y) * wv.y + b2f(a4.z) * wv.z + b2f(a4.w) * wv.w;
#pragma unroll
    for (int off = 32; off >= 1; off >>= 1) s += __shfl_xor(s, off);
    if (lane == 0) out[m0 + row] = 1.f / (1.f + expf(-(s + bf)));
  }
}

extern "C" void kernel_launch(void* const* d_in, const int* in_sizes, int n_in,
                              void* d_out, int out_size, void* d_ws, size_t ws_size,
                              hipStream_t stream) {
  const float* dense_x = (const float*)d_in[0];
  const int* lS_i = (const int*)d_in[2];
  const float* emb = (const float*)d_in[3];
  const float* bw0 = (const float*)d_in[4];
  const float* bb0 = (const float*)d_in[5];
  const float* bw1 = (const float*)d_in[6];
  const float* bb1 = (const float*)d_in[7];
  const float* bw2 = (const float*)d_in[8];
  const float* bb2 = (const float*)d_in[9];
  const float* tw0 = (const float*)d_in[10];
  const float* tb0 = (const float*)d_in[11];
  const float* tw1 = (const float*)d_in[12];
  const float* tb1 = (const float*)d_in[13];
  const float* tw2 = (const float*)d_in[14];
  const float* tb2 = (const float*)d_in[15];
  const float* tw3 = (const float*)d_in[16];
  const float* tb3 = (const float*)d_in[17];
  float* out = (float*)d_out;

  // workspace layout (bf16)
  char* w = (char*)d_ws;
  ushort* xb  = (ushort*)w; w += (size_t)BATCH * 128 * 2;
  ushort* x1  = (ushort*)w; w += (size_t)BATCH * 512 * 2;
  ushort* x2  = (ushort*)w; w += (size_t)BATCH * 256 * 2;
  ushort* R   = (ushort*)w; w += (size_t)BATCH * 512 * 2;
  ushort* t1  = (ushort*)w; w += (size_t)BATCH * 1024 * 2;
  ushort* wb1 = (ushort*)w; w += 256 * 512 * 2;
  ushort* wb2 = (ushort*)w; w += 128 * 256 * 2;
  ushort* wt0 = (ushort*)w; w += 1024 * 512 * 2;
  ushort* wt1 = (ushort*)w; w += 512 * 1024 * 2;
  ushort* wt2 = (ushort*)w; w += 256 * 512 * 2;
  ushort* t2 = x1;   // reuse (B x 512)

  // prep: bot0 + all weight conversions (one launch)
  prep_kernel<<<2 * BATCH + 5 * 2048, 256, 0, stream>>>(
      dense_x, bw0, bb0, x1, bw1, bw2, tw0, tw1, tw2, wb1, wb2, wt0, wt1, wt2);

  // bottom MLP -> xb (packed B x 128)
  gemm_bf16_kernel<1><<<dim3(2, BATCH / 128), 256, 0, stream>>>(x1, wb1, bb1, x2, 512, 256);
  gemm_bf16_kernel<1><<<dim3(1, BATCH / 128), 256, 0, stream>>>(x2, wb2, bb2, xb, 256, 128);

  // fused embeddings + interaction -> R = [x | tril(Z) | 0pad]
  embint_kernel<<<BATCH / 4, 256, 0, stream>>>(emb, lS_i, xb, R);

  // top MLP
  gemm256_kernel<1><<<dim3(1024 / 128, BATCH / 256), 512, 0, stream>>>(R,  wt0, tb0, t1, 512, 1024);
  gemm256_kernel<1><<<dim3(512 / 128,  BATCH / 256), 512, 0, stream>>>(t1, wt1, tb1, t2, 1024, 512);
  t2final_kernel<<<BATCH / 64, 256, 0, stream>>>(t2, wt2, tb2, tw3, tb3, out);
}